// Round 2
// baseline (1457.717 us; speedup 1.0000x reference)
//
#include <hip/hip_runtime.h>
#include <hip/hip_bf16.h>
#include <cstdint>
#include <cstddef>

#define B_   128
#define T_   50
#define M_   4
#define D_   64
#define K_   64
#define L_   16
#define NIT  100001
#define NB_P 256
#define CHUNK_P 391   /* 256*391 = 100096 >= NIT */

typedef unsigned short u16;
typedef unsigned int   u32;

__device__ __forceinline__ float bf2f(u16 v){ u32 u = ((u32)v)<<16; float f; __builtin_memcpy(&f,&u,4); return f; }
__device__ __forceinline__ u16 f2bf(float f){
  u32 u; __builtin_memcpy(&u,&f,4);
  u32 r = (u + 0x7FFFu + ((u>>16)&1u)) >> 16;
  return (u16)r;
}
__device__ __forceinline__ float fexp(float x){ return __builtin_amdgcn_exp2f(x*1.4426950408889634f); }
__device__ __forceinline__ float fsig(float x){ return __builtin_amdgcn_rcpf(1.0f + fexp(-x)); }
__device__ __forceinline__ float ftanh(float x){ return 1.0f - 2.0f*__builtin_amdgcn_rcpf(1.0f + fexp(2.0f*x)); }

// ---------------- transpose Wx[m][d][g] -> WxT[m][g][d] ----------------
__global__ __launch_bounds__(256) void k_wxt(const float* __restrict__ Wx, float* __restrict__ WxT)
{
  __shared__ float tl[64][65];
  int m = blockIdx.x / 48, gt = blockIdx.x % 48;
  for (int it=0; it<16; ++it){
    int li = threadIdx.x + it*256;
    int dl = li >> 6, gl = li & 63;
    tl[dl][gl] = Wx[((size_t)m*64 + dl)*3072 + gt*64 + gl];
  }
  __syncthreads();
  for (int it=0; it<16; ++it){
    int li = threadIdx.x + it*256;
    int gl = li >> 6, dl = li & 63;
    WxT[((size_t)m*3072 + gt*64 + gl)*64 + dl] = tl[dl][gl];
  }
}

// ---------------- gi = embed(x)@Wx + bx (+bh fold for r,z gates), bf16 out ----------------
// layout gi[m][k][t][b][gate*16+j]
__global__ __launch_bounds__(256,3) void k_gi(const int* __restrict__ s0, const int* __restrict__ s1,
  const int* __restrict__ s2, const int* __restrict__ s3, const float* __restrict__ E,
  const float* __restrict__ WxT, const float* __restrict__ bx, const float* __restrict__ bhp,
  u16* __restrict__ gi)
{
  int wave = threadIdx.x>>6, lane = threadIdx.x&63;
  int bi = blockIdx.x;
  int kc = bi & 15; bi >>= 4;
  int rowBlk = bi % 25, m = bi/25;
  int row = rowBlk*256 + wave*64 + lane;        // row = t*128+b
  int t = row >> 7, b = row & 127;
  const int* sq = (m==0)? s0 : (m==1)? s1 : (m==2)? s2 : s3;
  int idx = sq[b*T_ + t];
  float msk = (idx==0)? 0.0f : 1.0f;
  float xr[64];
  const float4* xp = (const float4*)(E + (size_t)idx*64);
  #pragma unroll
  for (int q=0;q<16;q++){ float4 v = xp[q];
    xr[4*q]=v.x*msk; xr[4*q+1]=v.y*msk; xr[4*q+2]=v.z*msk; xr[4*q+3]=v.w*msk; }
  for (int kk=0;kk<4;kk++){
    int k = kc*4+kk;
    u32 outw[24];
    #pragma unroll
    for (int g4=0; g4<12; ++g4){
      float acc[4];
      const float4* wp[4];
      #pragma unroll
      for (int z=0; z<4; ++z){
        int gg = g4*4+z; int gate = gg>>4, j = gg&15; int g = (gate*64 + k)*16 + j;
        acc[z] = bx[m*3072 + g] + ((gate<2)? bhp[(m*64+k)*48 + gg] : 0.0f);
        wp[z] = (const float4*)(WxT + ((size_t)m*3072 + g)*64);
      }
      #pragma unroll
      for (int q=0;q<16;q++){
        float4 a = wp[0][q], c = wp[1][q], e = wp[2][q], f = wp[3][q];
        acc[0] += a.x*xr[4*q] + a.y*xr[4*q+1] + a.z*xr[4*q+2] + a.w*xr[4*q+3];
        acc[1] += c.x*xr[4*q] + c.y*xr[4*q+1] + c.z*xr[4*q+2] + c.w*xr[4*q+3];
        acc[2] += e.x*xr[4*q] + e.y*xr[4*q+1] + e.z*xr[4*q+2] + e.w*xr[4*q+3];
        acc[3] += f.x*xr[4*q] + f.y*xr[4*q+1] + f.z*xr[4*q+2] + f.w*xr[4*q+3];
      }
      outw[g4*2]   = (u32)f2bf(acc[0]) | ((u32)f2bf(acc[1])<<16);
      outw[g4*2+1] = (u32)f2bf(acc[2]) | ((u32)f2bf(acc[3])<<16);
    }
    u32* dst = (u32*)(gi + (((size_t)((m*64+k)*50 + t)*128 + b)*48));
    #pragma unroll
    for (int q=0;q<6;q++){
      uint4 w4; w4.x=outw[4*q]; w4.y=outw[4*q+1]; w4.z=outw[4*q+2]; w4.w=outw[4*q+3];
      ((uint4*)dst)[q] = w4;
    }
  }
}

// ---------------- GRU scan: 16 lanes per (b,m,k) chain ----------------
// RC: add C-term N*r live. WN: write candidate n to Nbuf.
template<int RC, int WN>
__global__ __launch_bounds__(256,4) void k_gru(const u16* __restrict__ gi, const float* __restrict__ Wh,
  const float* __restrict__ bhp, const float* __restrict__ rp,
  u16* __restrict__ Nbuf, float* __restrict__ behE)
{
  __shared__ float hbuf[256];
  int tid = threadIdx.x;
  int wave = tid>>6, lane = tid&63;
  int bg = lane>>4, j = lane&15;
  int bi = blockIdx.x;
  int bblk = bi & 7; bi >>= 3;
  int k = bi & 63; int m = bi >> 6;
  int b = bblk*16 + wave*4 + bg;
  float wr[16], wz[16], wn[16];
  const float* whp = Wh + ((size_t)(m*64+k)*16)*48;
  #pragma unroll
  for (int l=0;l<16;l++){
    wr[l] = whp[l*48 + j];
    wz[l] = whp[l*48 + 16 + j];
    wn[l] = whp[l*48 + 32 + j];
  }
  float bhn = bhp[(m*64+k)*48 + 32 + j];
  float rv = 0.f;
  if (RC) rv = rp[((size_t)b*64+k)*16 + j];
  float hown = 0.0f;
  hbuf[tid] = 0.0f;
  __builtin_amdgcn_wave_barrier();
  int gBase = (((m*64+k)*50)*128 + b)*48 + j;
  int nBase = (((m*64+k)*50)*128 + b)*16 + j;
  const float* hgrp = &hbuf[tid & ~15];
  for (int t=0;t<50;++t){
    float gir = bf2f(gi[gBase]);
    float giz = bf2f(gi[gBase+16]);
    float gin = bf2f(gi[gBase+32]);
    float Ct = 0.0f;
    if (RC) Ct = bf2f(Nbuf[nBase]) * rv;
    float hv[16];
    *(float4*)&hv[0]  = ((const float4*)hgrp)[0];
    *(float4*)&hv[4]  = ((const float4*)hgrp)[1];
    *(float4*)&hv[8]  = ((const float4*)hgrp)[2];
    *(float4*)&hv[12] = ((const float4*)hgrp)[3];
    float ghr = 0.f, ghz = 0.f, ghn = bhn;
    #pragma unroll
    for (int l=0;l<16;l++){ ghr += hv[l]*wr[l]; ghz += hv[l]*wz[l]; ghn += hv[l]*wn[l]; }
    float rg = fsig(gir + ghr);
    float zg = fsig(giz + ghz + Ct);
    float ng = ftanh(gin + rg*ghn);
    float hn = ng + zg*(hown - ng);
    if (WN) Nbuf[nBase] = f2bf(ng);
    hown = hn;
    __builtin_amdgcn_wave_barrier();
    hbuf[tid] = hn;
    __builtin_amdgcn_wave_barrier();
    gBase += 128*48;
    nBase += 128*16;
  }
  behE[(((size_t)b*64 + k)*4 + m)*16 + j] = hown;
}

// ---------------- fold C-term into gi z-plane in place: giz += N*r ----------------
__global__ __launch_bounds__(256) void k_addC(u16* __restrict__ gi, const u16* __restrict__ N,
  const float* __restrict__ r)
{
  int id = blockIdx.x*256 + threadIdx.x;
  int row = id >> 1, half = id & 1;      // row = ((m*64+k)*50+t)*128+b
  int b = row & 127;
  int mk = row / 6400;
  int k = mk & 63;
  u16* gz = gi + (size_t)row*48 + 16 + half*8;
  const u16* np = N + (size_t)row*16 + half*8;
  const float* rv = r + ((size_t)b*64 + k)*16 + half*8;
  uint4 gv = *(const uint4*)gz;
  uint4 nv = *(const uint4*)np;
  float4 r0 = ((const float4*)rv)[0];
  float4 r1 = ((const float4*)rv)[1];
  u32 go[4]; u32 gin[4] = {gv.x,gv.y,gv.z,gv.w}; u32 nin[4] = {nv.x,nv.y,nv.z,nv.w};
  float rr[8] = {r0.x,r0.y,r0.z,r0.w,r1.x,r1.y,r1.z,r1.w};
  #pragma unroll
  for (int q=0;q<4;q++){
    float g0 = bf2f((u16)(gin[q]&0xFFFF)), g1 = bf2f((u16)(gin[q]>>16));
    float n0 = bf2f((u16)(nin[q]&0xFFFF)), n1 = bf2f((u16)(nin[q]>>16));
    g0 += n0*rr[2*q]; g1 += n1*rr[2*q+1];
    go[q] = (u32)f2bf(g0) | ((u32)f2bf(g1)<<16);
  }
  uint4 ov; ov.x=go[0]; ov.y=go[1]; ov.z=go[2]; ov.w=go[3];
  *(uint4*)gz = ov;
}

// ---------------- softmax(b)+v+v_ with on-the-fly u recompute ----------------
__global__ __launch_bounds__(256) void k_cv(const float* __restrict__ bmat, const float* __restrict__ behE,
  const float* __restrict__ W, const float* __restrict__ alpha, const float* __restrict__ wv,
  const float* __restrict__ bias, float* __restrict__ vout, float* __restrict__ vT)
{
  __shared__ float cm[64][65];
  __shared__ float vsh[64][17];
  __shared__ float besh[4096];
  int b = blockIdx.x, tid = threadIdx.x;
  for (int it=0; it<16; ++it){
    int li = tid + it*256;
    cm[li>>6][li&63] = bmat[(size_t)b*4096 + li];
    besh[li] = behE[(size_t)b*4096 + li];
  }
  __syncthreads();
  if (tid < 64){
    float mx = -1e30f;
    for (int jj=0;jj<64;jj++) mx = fmaxf(mx, cm[tid][jj]);
    float sm = 0.f;
    for (int jj=0;jj<64;jj++){ float e = fexp(cm[tid][jj]-mx); cm[tid][jj]=e; sm+=e; }
    float inv = 1.0f/sm;
    for (int jj=0;jj<64;jj++) cm[tid][jj] *= inv;
  }
  __syncthreads();
  int j = tid & 63, dq = tid>>6;
  float a0=0,a1=0,a2=0,a3=0;
  for (int i=0;i<64;++i){
    float cij = cm[i][j];
    #pragma unroll
    for (int q=0;q<4;++q){
      int d = dq*4+q;
      const float* wp = W + ((size_t)((i*16+d)*4))*64 + j;
      float uu = besh[i*64+d]*wp[0] + besh[i*64+16+d]*wp[64]
               + besh[i*64+32+d]*wp[128] + besh[i*64+48+d]*wp[192];
      float cu = cij*uu;
      if (q==0) a0 += cu; else if (q==1) a1 += cu; else if (q==2) a2 += cu; else a3 += cu;
    }
  }
  float al = alpha[0];
  a0*=al; a1*=al; a2*=al; a3*=al;
  vsh[j][dq*4]=a0; vsh[j][dq*4+1]=a1; vsh[j][dq*4+2]=a2; vsh[j][dq*4+3]=a3;
  float* vp = vout + ((size_t)b*64 + j)*16 + dq*4;
  vp[0]=a0; vp[1]=a1; vp[2]=a2; vp[3]=a3;
  __syncthreads();
  if (tid < 64){
    float s=0.f;
    #pragma unroll
    for (int dd=0; dd<16; ++dd){ float q = vsh[tid][dd]; s += q*q; }
    vT[tid*128 + b] = sqrtf(s)*wv[tid] + bias[tid];
  }
}

// ---------------- fused logits+softmax+p partials (no max: logits are tiny) ----------------
__global__ __launch_bounds__(256,2) void k_pfused(const float* __restrict__ vT, const float* __restrict__ E,
  float* __restrict__ partial)
{
  __shared__ float pb[128][65];
  __shared__ float sb[2][128];
  int tid = threadIdx.x, lane = tid&63, w = tid>>6;
  int bh = w & 1, ih = w >> 1;
  int b = bh*64 + lane;
  float vr[64];
  #pragma unroll
  for (int kk=0;kk<64;kk++) vr[kk] = vT[kk*128 + b];
  float acc[64];
  #pragma unroll
  for (int q=0;q<64;q++) acc[q]=0.f;
  float srun = 0.f;
  int start = blockIdx.x*CHUNK_P;
  int end = start + CHUNK_P; if (end > NIT) end = NIT;
  for (int i = start + ih; i < end; i += 2){
    const float4* er = (const float4*)(E + (size_t)i*64);
    float s0=0,s1=0,s2=0,s3=0;
    #pragma unroll
    for (int q=0;q<16;q++){
      float4 e = er[q];
      s0 += e.x*vr[4*q]; s1 += e.y*vr[4*q+1]; s2 += e.z*vr[4*q+2]; s3 += e.w*vr[4*q+3];
    }
    float ex = fexp((s0+s1)+(s2+s3));
    srun += ex;
    #pragma unroll
    for (int q=0;q<16;q++){
      float4 e = er[q];
      acc[4*q+0] += ex*e.x; acc[4*q+1] += ex*e.y; acc[4*q+2] += ex*e.z; acc[4*q+3] += ex*e.w;
    }
  }
  if (ih == 0){
    #pragma unroll
    for (int q=0;q<64;q++) pb[b][q] = acc[q];
    sb[0][b] = srun;
  }
  __syncthreads();
  if (ih == 1){
    #pragma unroll
    for (int q=0;q<64;q++) pb[b][q] += acc[q];
    sb[1][b] = srun;
  }
  __syncthreads();
  float* dst = partial + (size_t)blockIdx.x*8448;
  for (int it=0; it<33; ++it){
    int li = tid + it*256;
    int bb = li/66, cc = li%66;
    float val = (cc<64)? pb[bb][cc] : ((cc==64)? (sb[0][bb]+sb[1][bb]) : 0.f);
    dst[li] = val;
  }
}

__global__ __launch_bounds__(256) void k_pcomb(const float* __restrict__ partial, float* __restrict__ p)
{
  int id = blockIdx.x*256 + threadIdx.x;   // b*64+d
  int b = id>>6, d = id&63;
  float a = 0.f, s = 0.f;
  for (int q=0;q<NB_P;q++){
    const float* pp = partial + (size_t)q*8448 + b*66;
    a += pp[d]; s += pp[64];
  }
  p[id] = a/s;
}

// ---------------- r[b][j][l] = sum_d cat(p,v)[b,j,d]*Wc[j][d][l] ----------------
__global__ __launch_bounds__(256) void k_r(const float* __restrict__ p, const float* __restrict__ v,
  const float* __restrict__ Wc, float* __restrict__ r, float* __restrict__ rT)
{
  int gid = blockIdx.x*256 + threadIdx.x;
  int l = gid & 15, j = (gid>>4)&63, b = gid>>10;
  const float* wc = Wc + ((size_t)j*80)*16 + l;
  const float* pbp = p + b*64;
  float acc = 0.f;
  #pragma unroll 8
  for (int d=0; d<64; ++d) acc += pbp[d]*wc[d*16];
  const float* vb = v + ((size_t)b*64 + j)*16;
  #pragma unroll
  for (int d=0; d<16; ++d) acc += vb[d]*wc[(64+d)*16];
  r[((size_t)b*64+j)*16 + l] = acc;
  rT[((size_t)b*16+l)*64 + j] = acc;
}

// ---------------- b[b][i][j] += sum_d u[b][i][d][j]*r[b][j][d], u recomputed ----------------
__global__ __launch_bounds__(256) void k_bupd(const float* __restrict__ behE, const float* __restrict__ W,
  const float* __restrict__ rT, float* __restrict__ bmat)
{
  int lane = threadIdx.x & 63;
  int idx = blockIdx.x*4 + (threadIdx.x>>6);   // b*64+i
  int b = idx >> 6, i = idx & 63;
  const float* be = behE + (size_t)idx*64;     // behE[b][i][m][d], 64 floats
  const float* rp = rT + (size_t)b*1024;       // rT[b][d][j]
  float acc = 0.f;
  #pragma unroll
  for (int d=0; d<16; ++d){
    const float* wp = W + ((size_t)((i*16+d)*4))*64 + lane;
    float uu = be[d]*wp[0] + be[16+d]*wp[64] + be[32+d]*wp[128] + be[48+d]*wp[192];
    acc += uu * rp[d*64 + lane];
  }
  bmat[(size_t)idx*64 + lane] += acc;
}

// ---------------- logits[b][i] = sum_k vT[k][b]*E[i][k] ----------------
__global__ __launch_bounds__(128) void k_logits(const float* __restrict__ vT, const float* __restrict__ E,
  float* __restrict__ out, int ld, int storeW)
{
  __shared__ float tile[128][33];
  int tid = threadIdx.x, lane = tid & 63, bh2 = tid>>6;
  int b = bh2*64 + lane;
  float vr[64];
  #pragma unroll
  for (int kk=0;kk<64;kk++) vr[kk] = vT[kk*128 + b];
  int i0 = blockIdx.x*32;
  for (int ii=0; ii<32; ++ii){
    int i = i0 + ii;
    float acc = 0.0f;
    if (i < NIT){
      const float4* er = (const float4*)(E + (size_t)i*64);
      float s0=0,s1=0,s2=0,s3=0;
      #pragma unroll
      for (int q=0;q<16;q++){
        float4 e = er[q];
        s0 += e.x*vr[4*q]; s1 += e.y*vr[4*q+1]; s2 += e.z*vr[4*q+2]; s3 += e.w*vr[4*q+3];
      }
      acc = (s0+s1)+(s2+s3);
    }
    tile[b][ii] = acc;
  }
  __syncthreads();
  int nv = storeW - i0; if (nv > 32) nv = 32; if (nv < 0) nv = 0;
  float* op = out + (size_t)tid*ld + i0;
  for (int ii=0; ii<nv; ++ii) op[ii] = tile[tid][ii];
}

extern "C" void kernel_launch(void* const* d_in, const int* in_sizes, int n_in,
                              void* d_out, int out_size, void* d_ws, size_t ws_size,
                              hipStream_t stream)
{
  (void)in_sizes; (void)n_in; (void)out_size; (void)ws_size;
  const int*   s0 = (const int*)d_in[0];
  const int*   s1 = (const int*)d_in[1];
  const int*   s2 = (const int*)d_in[2];
  const int*   s3 = (const int*)d_in[3];
  const float* E  = (const float*)d_in[4];
  const float* W  = (const float*)d_in[5];
  const float* Wc = (const float*)d_in[6];
  const float* alpha = (const float*)d_in[7];
  const float* wv    = (const float*)d_in[8];
  const float* bias  = (const float*)d_in[9];
  const float* Wx = (const float*)d_in[10];
  const float* bx = (const float*)d_in[11];
  const float* Wh = (const float*)d_in[12];
  const float* bh = (const float*)d_in[13];

  char* ws = (char*)d_ws;
  size_t off = 0;
  auto alloc = [&](size_t bytes)->void*{ void* q = ws + off; off += (bytes + 255) & ~(size_t)255; return q; };
  u16*   gi   = (u16*)  alloc((size_t)M_*K_*T_*B_*48*2);   // 157.3 MB
  u16*   N1   = (u16*)  alloc((size_t)M_*K_*T_*B_*16*2);   // 52.4 MB (single N buffer)
  float* WxT  = (float*)alloc((size_t)M_*3072*64*4);       // 3.1 MB
  float* bmat = (float*)alloc((size_t)B_*64*64*4);         // 2.1 MB
  float* behE = (float*)alloc((size_t)B_*64*4*16*4);       // 2.1 MB
  float* v    = (float*)alloc((size_t)B_*64*16*4);
  float* vT   = (float*)alloc((size_t)64*128*4);
  float* r1   = (float*)alloc((size_t)B_*64*16*4);
  float* rT1  = (float*)alloc((size_t)B_*64*16*4);
  float* r2   = (float*)alloc((size_t)B_*64*16*4);
  float* rT2  = (float*)alloc((size_t)B_*64*16*4);
  float* p    = (float*)alloc((size_t)B_*64*4);
  float* partial = (float*)alloc((size_t)NB_P*8448*4);     // 8.65 MB
  // total ~228.5 MB

  hipMemsetAsync(bmat, 0, (size_t)B_*64*64*4, stream);
  k_wxt<<<192,256,0,stream>>>(Wx,WxT);
  k_gi<<<1600,256,0,stream>>>(s0,s1,s2,s3,E,WxT,bx,bh,gi);

  // ---- routing iteration 1 ----
  k_gru<0,1><<<2048,256,0,stream>>>(gi,Wh,bh,nullptr,N1,behE);
  k_cv<<<128,256,0,stream>>>(bmat,behE,W,alpha,wv,bias,v,vT);
  k_pfused<<<NB_P,256,0,stream>>>(vT,E,partial);
  k_pcomb<<<32,256,0,stream>>>(partial,p);
  k_r<<<512,256,0,stream>>>(p,v,Wc,r1,rT1);
  k_bupd<<<2048,256,0,stream>>>(behE,W,rT1,bmat);
  k_addC<<<12800,256,0,stream>>>(gi,N1,r1);     // fold C1 = N1*r1 into gi z-plane

  // ---- routing iteration 2 ----
  k_gru<0,1><<<2048,256,0,stream>>>(gi,Wh,bh,nullptr,N1,behE);   // overwrites N with N2
  k_cv<<<128,256,0,stream>>>(bmat,behE,W,alpha,wv,bias,v,vT);
  k_pfused<<<NB_P,256,0,stream>>>(vT,E,partial);
  k_pcomb<<<32,256,0,stream>>>(partial,p);
  k_r<<<512,256,0,stream>>>(p,v,Wc,r2,rT2);
  k_bupd<<<2048,256,0,stream>>>(behE,W,rT2,bmat);

  // ---- final pass: C = (folded C1) + N2*r2 live ----
  k_gru<1,0><<<2048,256,0,stream>>>(gi,Wh,bh,r2,N1,behE);
  k_cv<<<128,256,0,stream>>>(bmat,behE,W,alpha,wv,bias,v,vT);
  k_logits<<<3126,128,0,stream>>>(vT,E,(float*)d_out,NIT,NIT);
}

// Round 3
// 1433.787 us; speedup vs baseline: 1.0167x; 1.0167x over previous
//
#include <hip/hip_runtime.h>
#include <hip/hip_bf16.h>
#include <cstdint>
#include <cstddef>

#define B_   128
#define T_   50
#define M_   4
#define D_   64
#define K_   64
#define L_   16
#define NIT  100001
#define NB_P 128
#define CHUNK_P 782   /* 128*782 = 100096 >= NIT */

typedef unsigned short u16;
typedef unsigned int   u32;
typedef __attribute__((ext_vector_type(8))) short short8;
typedef __attribute__((ext_vector_type(4))) float f32x4;

__device__ __forceinline__ float bf2f(u16 v){ u32 u = ((u32)v)<<16; float f; __builtin_memcpy(&f,&u,4); return f; }
__device__ __forceinline__ u16 f2bf(float f){
  u32 u; __builtin_memcpy(&u,&f,4);
  u32 r = (u + 0x7FFFu + ((u>>16)&1u)) >> 16;
  return (u16)r;
}
__device__ __forceinline__ float fexp(float x){ return __builtin_amdgcn_exp2f(x*1.4426950408889634f); }
__device__ __forceinline__ float fsig(float x){ return __builtin_amdgcn_rcpf(1.0f + fexp(-x)); }
__device__ __forceinline__ float ftanh(float x){ return 1.0f - 2.0f*__builtin_amdgcn_rcpf(1.0f + fexp(2.0f*x)); }

// ---------------- prep x: embed+mask, split fp32 -> bf16 hi/lo, layout [m][t*128+b][64] ----------------
__global__ __launch_bounds__(256) void k_prep_x(const int* __restrict__ s0, const int* __restrict__ s1,
  const int* __restrict__ s2, const int* __restrict__ s3, const float* __restrict__ E,
  u16* __restrict__ xh, u16* __restrict__ xl)
{
  int id = blockIdx.x*256 + threadIdx.x;     // 204800 = 4*6400*8
  int e8 = id & 7;
  int rm = id >> 3;                          // m*6400 + r
  int m = rm / 6400; int r = rm - m*6400;
  int t = r >> 7, b = r & 127;
  const int* sq = (m==0)? s0 : (m==1)? s1 : (m==2)? s2 : s3;
  int idx = sq[b*T_ + t];
  float sc = (idx==0)? 0.0f : 1.0f;
  const float4* ep = (const float4*)(E + (size_t)idx*64 + e8*8);
  float4 v0 = ep[0], v1 = ep[1];
  float vals[8] = {v0.x,v0.y,v0.z,v0.w,v1.x,v1.y,v1.z,v1.w};
  u32 hw[4], lw[4];
  #pragma unroll
  for (int q=0;q<4;q++){
    float f0 = vals[2*q]*sc, f1 = vals[2*q+1]*sc;
    u16 h0 = f2bf(f0), h1 = f2bf(f1);
    u16 l0 = f2bf(f0 - bf2f(h0)), l1 = f2bf(f1 - bf2f(h1));
    hw[q] = (u32)h0 | ((u32)h1<<16);
    lw[q] = (u32)l0 | ((u32)l1<<16);
  }
  size_t off = (size_t)rm*64 + e8*8;
  uint4 hv; hv.x=hw[0]; hv.y=hw[1]; hv.z=hw[2]; hv.w=hw[3];
  uint4 lv; lv.x=lw[0]; lv.y=lw[1]; lv.z=lw[2]; lv.w=lw[3];
  *(uint4*)(xh + off) = hv;
  *(uint4*)(xl + off) = lv;
}

// ---------------- prep W: transpose Wx[m][d][g] -> [m][g][d], split bf16 hi/lo ----------------
__global__ __launch_bounds__(256) void k_prep_w(const float* __restrict__ Wx,
  u16* __restrict__ wh, u16* __restrict__ wl)
{
  __shared__ float tl[64][65];
  int m = blockIdx.x / 48, gt = blockIdx.x % 48;
  for (int it=0; it<16; ++it){
    int li = threadIdx.x + it*256;
    int dl = li >> 6, gl = li & 63;
    tl[dl][gl] = Wx[((size_t)m*64 + dl)*3072 + gt*64 + gl];
  }
  __syncthreads();
  for (int it=0; it<2; ++it){
    int unit = threadIdx.x + it*256;          // 512 units: gl*8 + d8
    int gl = unit >> 3, d8 = unit & 7;
    u32 hw[4], lw[4];
    #pragma unroll
    for (int q=0;q<4;q++){
      float f0 = tl[d8*8+2*q][gl], f1 = tl[d8*8+2*q+1][gl];
      u16 h0 = f2bf(f0), h1 = f2bf(f1);
      u16 l0 = f2bf(f0 - bf2f(h0)), l1 = f2bf(f1 - bf2f(h1));
      hw[q] = (u32)h0 | ((u32)h1<<16);
      lw[q] = (u32)l0 | ((u32)l1<<16);
    }
    size_t off = ((size_t)m*3072 + gt*64 + gl)*64 + d8*8;
    uint4 hv; hv.x=hw[0]; hv.y=hw[1]; hv.z=hw[2]; hv.w=hw[3];
    uint4 lv; lv.x=lw[0]; lv.y=lw[1]; lv.z=lw[2]; lv.w=lw[3];
    *(uint4*)(wh + off) = hv;
    *(uint4*)(wl + off) = lv;
  }
}

// ---------------- gi GEMM via MFMA: D[j(16), rows(16)] per tile; split-bf16 for fp32 accuracy ----------------
// gi[m][k][t][b][gate*16+j], bias bx + bh fold for gates r,z
__global__ __launch_bounds__(256) void k_gemm_gi(const u16* __restrict__ xh, const u16* __restrict__ xl,
  const u16* __restrict__ wh, const u16* __restrict__ wl,
  const float* __restrict__ bx, const float* __restrict__ bhp, u16* __restrict__ gi)
{
  int bi = blockIdx.x;
  int q4 = bi & 3; int k = (bi>>2)&63; int m = bi>>8;
  int wv = threadIdx.x>>6, lane = threadIdx.x&63;
  int n16 = lane & 15, quad = lane >> 4;

  short8 Ah[3][2], Al[3][2];
  #pragma unroll
  for (int gate=0; gate<3; ++gate){
    int g = gate*1024 + k*16 + n16;           // A m-index = j
    #pragma unroll
    for (int c=0; c<2; ++c){
      size_t aoff = ((size_t)(m*3072 + g))*64 + c*32 + quad*8;
      Ah[gate][c] = *(const short8*)(wh + aoff);
      Al[gate][c] = *(const short8*)(wl + aoff);
    }
  }
  float bias[3][4];
  #pragma unroll
  for (int gate=0; gate<3; ++gate){
    #pragma unroll
    for (int rg=0; rg<4; ++rg){
      int j = quad*4 + rg;
      int g = gate*1024 + k*16 + j;
      bias[gate][rg] = bx[m*3072 + g] + ((gate<2)? bhp[(m*64+k)*48 + gate*16 + j] : 0.0f);
    }
  }
  for (int i=0; i<25; ++i){
    int row = q4*1600 + (i*4+wv)*16 + n16;    // x row = t*128+b
    size_t xoff = ((size_t)(m*6400 + row))*64 + quad*8;
    short8 Bh0 = *(const short8*)(xh + xoff);
    short8 Bh1 = *(const short8*)(xh + xoff + 32);
    short8 Bl0 = *(const short8*)(xl + xoff);
    short8 Bl1 = *(const short8*)(xl + xoff + 32);
    #pragma unroll
    for (int gate=0; gate<3; ++gate){
      f32x4 acc = {bias[gate][0], bias[gate][1], bias[gate][2], bias[gate][3]};
      acc = __builtin_amdgcn_mfma_f32_16x16x32_bf16(Ah[gate][0], Bh0, acc, 0,0,0);
      acc = __builtin_amdgcn_mfma_f32_16x16x32_bf16(Ah[gate][1], Bh1, acc, 0,0,0);
      acc = __builtin_amdgcn_mfma_f32_16x16x32_bf16(Al[gate][0], Bh0, acc, 0,0,0);
      acc = __builtin_amdgcn_mfma_f32_16x16x32_bf16(Al[gate][1], Bh1, acc, 0,0,0);
      acc = __builtin_amdgcn_mfma_f32_16x16x32_bf16(Ah[gate][0], Bl0, acc, 0,0,0);
      acc = __builtin_amdgcn_mfma_f32_16x16x32_bf16(Ah[gate][1], Bl1, acc, 0,0,0);
      u32 w0 = (u32)f2bf(acc[0]) | ((u32)f2bf(acc[1])<<16);
      u32 w1 = (u32)f2bf(acc[2]) | ((u32)f2bf(acc[3])<<16);
      size_t go = ((size_t)((m*64+k)*6400 + row))*48 + gate*16 + quad*4;
      uint2 st; st.x = w0; st.y = w1;
      *(uint2*)(gi + go) = st;
    }
  }
}

// ---------------- GRU scan: 16 lanes per (b,m,k) chain ----------------
// RC: C-term = N*r live. WN: write candidate n (overwrites Nbuf in place). FOLD: gi.z += C in place.
template<int RC, int WN, int FOLD>
__global__ __launch_bounds__(256,4) void k_gru(u16* __restrict__ gi, const float* __restrict__ Wh,
  const float* __restrict__ bhp, const float* __restrict__ rp,
  u16* __restrict__ Nbuf, float* __restrict__ behE)
{
  __shared__ float hbuf[256];
  int tid = threadIdx.x;
  int wave = tid>>6, lane = tid&63;
  int bg = lane>>4, j = lane&15;
  int bi = blockIdx.x;
  int bblk = bi & 7; bi >>= 3;
  int k = bi & 63; int m = bi >> 6;
  int b = bblk*16 + wave*4 + bg;
  float wr[16], wz[16], wn[16];
  const float* whp = Wh + ((size_t)(m*64+k)*16)*48;
  #pragma unroll
  for (int l=0;l<16;l++){
    wr[l] = whp[l*48 + j];
    wz[l] = whp[l*48 + 16 + j];
    wn[l] = whp[l*48 + 32 + j];
  }
  float bhn = bhp[(m*64+k)*48 + 32 + j];
  float rv = 0.f;
  if (RC) rv = rp[((size_t)b*64+k)*16 + j];
  float hown = 0.0f;
  hbuf[tid] = 0.0f;
  __builtin_amdgcn_wave_barrier();
  int gBase = (((m*64+k)*50)*128 + b)*48 + j;
  int nBase = (((m*64+k)*50)*128 + b)*16 + j;
  const float* hgrp = &hbuf[tid & ~15];
  for (int t=0;t<50;++t){
    float gir = bf2f(gi[gBase]);
    float giz = bf2f(gi[gBase+16]);
    float gin = bf2f(gi[gBase+32]);
    float Ct = 0.0f;
    if (RC) Ct = bf2f(Nbuf[nBase]) * rv;
    if (FOLD) gi[gBase+16] = f2bf(giz + Ct);
    float hv[16];
    *(float4*)&hv[0]  = ((const float4*)hgrp)[0];
    *(float4*)&hv[4]  = ((const float4*)hgrp)[1];
    *(float4*)&hv[8]  = ((const float4*)hgrp)[2];
    *(float4*)&hv[12] = ((const float4*)hgrp)[3];
    float ghr = 0.f, ghz = 0.f, ghn = bhn;
    #pragma unroll
    for (int l=0;l<16;l++){ ghr += hv[l]*wr[l]; ghz += hv[l]*wz[l]; ghn += hv[l]*wn[l]; }
    float rg = fsig(gir + ghr);
    float zg = fsig(giz + ghz + Ct);
    float ng = ftanh(gin + rg*ghn);
    float hn = ng + zg*(hown - ng);
    if (WN) Nbuf[nBase] = f2bf(ng);
    hown = hn;
    __builtin_amdgcn_wave_barrier();
    hbuf[tid] = hn;
    __builtin_amdgcn_wave_barrier();
    gBase += 128*48;
    nBase += 128*16;
  }
  behE[(((size_t)b*64 + k)*4 + m)*16 + j] = hown;
}

// ---------------- softmax(b)+v+v_ with on-the-fly u recompute ----------------
__global__ __launch_bounds__(256) void k_cv(const float* __restrict__ bmat, const float* __restrict__ behE,
  const float* __restrict__ W, const float* __restrict__ alpha, const float* __restrict__ wv,
  const float* __restrict__ bias, float* __restrict__ vout, float* __restrict__ vT)
{
  __shared__ float cm[64][65];
  __shared__ float vsh[64][17];
  __shared__ float besh[4096];
  int b = blockIdx.x, tid = threadIdx.x;
  for (int it=0; it<16; ++it){
    int li = tid + it*256;
    cm[li>>6][li&63] = bmat[(size_t)b*4096 + li];
    besh[li] = behE[(size_t)b*4096 + li];
  }
  __syncthreads();
  if (tid < 64){
    float mx = -1e30f;
    for (int jj=0;jj<64;jj++) mx = fmaxf(mx, cm[tid][jj]);
    float sm = 0.f;
    for (int jj=0;jj<64;jj++){ float e = fexp(cm[tid][jj]-mx); cm[tid][jj]=e; sm+=e; }
    float inv = 1.0f/sm;
    for (int jj=0;jj<64;jj++) cm[tid][jj] *= inv;
  }
  __syncthreads();
  int j = tid & 63, dq = tid>>6;
  float a0=0,a1=0,a2=0,a3=0;
  for (int i=0;i<64;++i){
    float cij = cm[i][j];
    #pragma unroll
    for (int q=0;q<4;++q){
      int d = dq*4+q;
      const float* wp = W + ((size_t)((i*16+d)*4))*64 + j;
      float uu = besh[i*64+d]*wp[0] + besh[i*64+16+d]*wp[64]
               + besh[i*64+32+d]*wp[128] + besh[i*64+48+d]*wp[192];
      float cu = cij*uu;
      if (q==0) a0 += cu; else if (q==1) a1 += cu; else if (q==2) a2 += cu; else a3 += cu;
    }
  }
  float al = alpha[0];
  a0*=al; a1*=al; a2*=al; a3*=al;
  vsh[j][dq*4]=a0; vsh[j][dq*4+1]=a1; vsh[j][dq*4+2]=a2; vsh[j][dq*4+3]=a3;
  float* vp = vout + ((size_t)b*64 + j)*16 + dq*4;
  vp[0]=a0; vp[1]=a1; vp[2]=a2; vp[3]=a3;
  __syncthreads();
  if (tid < 64){
    float s=0.f;
    #pragma unroll
    for (int dd=0; dd<16; ++dd){ float q = vsh[tid][dd]; s += q*q; }
    vT[tid*128 + b] = sqrtf(s)*wv[tid] + bias[tid];
  }
}

// ---------------- fused logits+softmax+p partials (no max: logits are tiny) ----------------
__global__ __launch_bounds__(256,2) void k_pfused(const float* __restrict__ vT, const float* __restrict__ E,
  float* __restrict__ partial)
{
  __shared__ float pb[128][65];
  __shared__ float sb[2][128];
  int tid = threadIdx.x, lane = tid&63, w = tid>>6;
  int bh = w & 1, ih = w >> 1;
  int b = bh*64 + lane;
  float vr[64];
  #pragma unroll
  for (int kk=0;kk<64;kk++) vr[kk] = vT[kk*128 + b];
  float acc[64];
  #pragma unroll
  for (int q=0;q<64;q++) acc[q]=0.f;
  float srun = 0.f;
  int start = blockIdx.x*CHUNK_P;
  int end = start + CHUNK_P; if (end > NIT) end = NIT;
  for (int i = start + ih; i < end; i += 2){
    const float4* er = (const float4*)(E + (size_t)i*64);
    float s0=0,s1=0,s2=0,s3=0;
    #pragma unroll
    for (int q=0;q<16;q++){
      float4 e = er[q];
      s0 += e.x*vr[4*q]; s1 += e.y*vr[4*q+1]; s2 += e.z*vr[4*q+2]; s3 += e.w*vr[4*q+3];
    }
    float ex = fexp((s0+s1)+(s2+s3));
    srun += ex;
    #pragma unroll
    for (int q=0;q<16;q++){
      float4 e = er[q];
      acc[4*q+0] += ex*e.x; acc[4*q+1] += ex*e.y; acc[4*q+2] += ex*e.z; acc[4*q+3] += ex*e.w;
    }
  }
  if (ih == 0){
    #pragma unroll
    for (int q=0;q<64;q++) pb[b][q] = acc[q];
    sb[0][b] = srun;
  }
  __syncthreads();
  if (ih == 1){
    #pragma unroll
    for (int q=0;q<64;q++) pb[b][q] += acc[q];
    sb[1][b] = srun;
  }
  __syncthreads();
  float* dst = partial + (size_t)blockIdx.x*8448;
  for (int it=0; it<33; ++it){
    int li = tid + it*256;
    int bb = li/66, cc = li%66;
    float val = (cc<64)? pb[bb][cc] : ((cc==64)? (sb[0][bb]+sb[1][bb]) : 0.f);
    dst[li] = val;
  }
}

__global__ __launch_bounds__(256) void k_pcomb(const float* __restrict__ partial, float* __restrict__ p)
{
  int id = blockIdx.x*256 + threadIdx.x;   // b*64+d
  int b = id>>6, d = id&63;
  float a = 0.f, s = 0.f;
  for (int q=0;q<NB_P;q++){
    const float* pp = partial + (size_t)q*8448 + b*66;
    a += pp[d]; s += pp[64];
  }
  p[id] = a/s;
}

// ---------------- r[b][j][l] = sum_d cat(p,v)[b,j,d]*Wc[j][d][l] ----------------
__global__ __launch_bounds__(256) void k_r(const float* __restrict__ p, const float* __restrict__ v,
  const float* __restrict__ Wc, float* __restrict__ r, float* __restrict__ rT)
{
  int gid = blockIdx.x*256 + threadIdx.x;
  int l = gid & 15, j = (gid>>4)&63, b = gid>>10;
  const float* wc = Wc + ((size_t)j*80)*16 + l;
  const float* pbp = p + b*64;
  float acc = 0.f;
  #pragma unroll 8
  for (int d=0; d<64; ++d) acc += pbp[d]*wc[d*16];
  const float* vb = v + ((size_t)b*64 + j)*16;
  #pragma unroll
  for (int d=0; d<16; ++d) acc += vb[d]*wc[(64+d)*16];
  r[((size_t)b*64+j)*16 + l] = acc;
  rT[((size_t)b*16+l)*64 + j] = acc;
}

// ---------------- b[b][i][j] += sum_d u[b][i][d][j]*r[b][j][d], u recomputed ----------------
__global__ __launch_bounds__(256) void k_bupd(const float* __restrict__ behE, const float* __restrict__ W,
  const float* __restrict__ rT, float* __restrict__ bmat)
{
  int lane = threadIdx.x & 63;
  int idx = blockIdx.x*4 + (threadIdx.x>>6);   // b*64+i
  int b = idx >> 6, i = idx & 63;
  const float* be = behE + (size_t)idx*64;
  const float* rp = rT + (size_t)b*1024;
  float acc = 0.f;
  #pragma unroll
  for (int d=0; d<16; ++d){
    const float* wp = W + ((size_t)((i*16+d)*4))*64 + lane;
    float uu = be[d]*wp[0] + be[16+d]*wp[64] + be[32+d]*wp[128] + be[48+d]*wp[192];
    acc += uu * rp[d*64 + lane];
  }
  bmat[(size_t)idx*64 + lane] += acc;
}

// ---------------- logits[b][i] = sum_k vT[k][b]*E[i][k] ----------------
__global__ __launch_bounds__(128) void k_logits(const float* __restrict__ vT, const float* __restrict__ E,
  float* __restrict__ out, int ld, int storeW)
{
  __shared__ float tile[128][33];
  int tid = threadIdx.x, lane = tid & 63, bh2 = tid>>6;
  int b = bh2*64 + lane;
  float vr[64];
  #pragma unroll
  for (int kk=0;kk<64;kk++) vr[kk] = vT[kk*128 + b];
  int i0 = blockIdx.x*32;
  for (int ii=0; ii<32; ++ii){
    int i = i0 + ii;
    float acc = 0.0f;
    if (i < NIT){
      const float4* er = (const float4*)(E + (size_t)i*64);
      float s0=0,s1=0,s2=0,s3=0;
      #pragma unroll
      for (int q=0;q<16;q++){
        float4 e = er[q];
        s0 += e.x*vr[4*q]; s1 += e.y*vr[4*q+1]; s2 += e.z*vr[4*q+2]; s3 += e.w*vr[4*q+3];
      }
      acc = (s0+s1)+(s2+s3);
    }
    tile[b][ii] = acc;
  }
  __syncthreads();
  int nv = storeW - i0; if (nv > 32) nv = 32; if (nv < 0) nv = 0;
  float* op = out + (size_t)tid*ld + i0;
  for (int ii=0; ii<nv; ++ii) op[ii] = tile[tid][ii];
}

extern "C" void kernel_launch(void* const* d_in, const int* in_sizes, int n_in,
                              void* d_out, int out_size, void* d_ws, size_t ws_size,
                              hipStream_t stream)
{
  (void)in_sizes; (void)n_in; (void)out_size; (void)ws_size;
  const int*   s0 = (const int*)d_in[0];
  const int*   s1 = (const int*)d_in[1];
  const int*   s2 = (const int*)d_in[2];
  const int*   s3 = (const int*)d_in[3];
  const float* E  = (const float*)d_in[4];
  const float* W  = (const float*)d_in[5];
  const float* Wc = (const float*)d_in[6];
  const float* alpha = (const float*)d_in[7];
  const float* wv    = (const float*)d_in[8];
  const float* bias  = (const float*)d_in[9];
  const float* Wx = (const float*)d_in[10];
  const float* bx = (const float*)d_in[11];
  const float* Wh = (const float*)d_in[12];
  const float* bh = (const float*)d_in[13];

  char* ws = (char*)d_ws;
  size_t off = 0;
  auto alloc = [&](size_t bytes)->void*{ void* q = ws + off; off += (bytes + 255) & ~(size_t)255; return q; };
  u16*   gi   = (u16*)  alloc((size_t)M_*K_*T_*B_*48*2);   // 157.3 MB
  u16*   N1   = (u16*)  alloc((size_t)M_*K_*T_*B_*16*2);   // 52.4 MB
  u16*   xh   = (u16*)  alloc((size_t)M_*6400*64*2);       // 3.28 MB
  u16*   xl   = (u16*)  alloc((size_t)M_*6400*64*2);       // 3.28 MB
  u16*   wh   = (u16*)  alloc((size_t)M_*3072*64*2);       // 1.57 MB
  u16*   wl   = (u16*)  alloc((size_t)M_*3072*64*2);       // 1.57 MB
  float* bmat = (float*)alloc((size_t)B_*64*64*4);         // 2.1 MB
  float* behE = (float*)alloc((size_t)B_*64*4*16*4);       // 2.1 MB
  float* v    = (float*)alloc((size_t)B_*64*16*4);
  float* vT   = (float*)alloc((size_t)64*128*4);
  float* r1   = (float*)alloc((size_t)B_*64*16*4);
  float* rT1  = (float*)alloc((size_t)B_*64*16*4);
  float* r2   = (float*)alloc((size_t)B_*64*16*4);
  float* rT2  = (float*)alloc((size_t)B_*64*16*4);
  float* p    = (float*)alloc((size_t)B_*64*4);
  float* partial = (float*)alloc((size_t)NB_P*8448*4);     // 4.33 MB
  // total ~231 MB

  hipMemsetAsync(bmat, 0, (size_t)B_*64*64*4, stream);
  k_prep_x<<<800,256,0,stream>>>(s0,s1,s2,s3,E,xh,xl);
  k_prep_w<<<192,256,0,stream>>>(Wx,wh,wl);
  k_gemm_gi<<<1024,256,0,stream>>>(xh,xl,wh,wl,bx,bh,gi);

  // ---- routing iteration 1 ----
  k_gru<0,1,0><<<2048,256,0,stream>>>(gi,Wh,bh,nullptr,N1,behE);
  k_cv<<<128,256,0,stream>>>(bmat,behE,W,alpha,wv,bias,v,vT);
  k_pfused<<<NB_P,256,0,stream>>>(vT,E,partial);
  k_pcomb<<<32,256,0,stream>>>(partial,p);
  k_r<<<512,256,0,stream>>>(p,v,Wc,r1,rT1);
  k_bupd<<<2048,256,0,stream>>>(behE,W,rT1,bmat);

  // ---- routing iteration 2: reads C1=N1*r1 live, folds it into gi.z, overwrites N with n2 ----
  k_gru<1,1,1><<<2048,256,0,stream>>>(gi,Wh,bh,r1,N1,behE);
  k_cv<<<128,256,0,stream>>>(bmat,behE,W,alpha,wv,bias,v,vT);
  k_pfused<<<NB_P,256,0,stream>>>(vT,E,partial);
  k_pcomb<<<32,256,0,stream>>>(partial,p);
  k_r<<<512,256,0,stream>>>(p,v,Wc,r2,rT2);
  k_bupd<<<2048,256,0,stream>>>(behE,W,rT2,bmat);

  // ---- final pass: C = (folded C1) + N2*r2 live ----
  k_gru<1,0,0><<<2048,256,0,stream>>>(gi,Wh,bh,r2,N1,behE);
  k_cv<<<128,256,0,stream>>>(bmat,behE,W,alpha,wv,bias,v,vT);
  k_logits<<<3126,128,0,stream>>>(vT,E,(float*)d_out,NIT,NIT);
}

// Round 4
// 1027.434 us; speedup vs baseline: 1.4188x; 1.3955x over previous
//
#include <hip/hip_runtime.h>
#include <hip/hip_bf16.h>
#include <cstdint>
#include <cstddef>

#define B_   128
#define T_   50
#define M_   4
#define D_   64
#define K_   64
#define L_   16
#define NIT  100001
#define NBP2 521
#define CHUNK2 192     /* 521*192 = 100032 >= NIT */
#define NBUCKET 8

typedef unsigned short u16;
typedef unsigned int   u32;
typedef __attribute__((ext_vector_type(8))) short short8;
typedef __attribute__((ext_vector_type(4))) float f32x4;

__device__ __forceinline__ float bf2f(u16 v){ u32 u = ((u32)v)<<16; float f; __builtin_memcpy(&f,&u,4); return f; }
__device__ __forceinline__ u16 f2bf(float f){
  u32 u; __builtin_memcpy(&u,&f,4);
  u32 r = (u + 0x7FFFu + ((u>>16)&1u)) >> 16;
  return (u16)r;
}
__device__ __forceinline__ float fexp(float x){ return __builtin_amdgcn_exp2f(x*1.4426950408889634f); }
__device__ __forceinline__ float fsig(float x){ return __builtin_amdgcn_rcpf(1.0f + fexp(-x)); }
__device__ __forceinline__ float ftanh(float x){ return 1.0f - 2.0f*__builtin_amdgcn_rcpf(1.0f + fexp(2.0f*x)); }

// ---------------- prep x: embed+mask, split fp32 -> bf16 hi/lo, layout [m][t*128+b][64] ----------------
__global__ __launch_bounds__(256) void k_prep_x(const int* __restrict__ s0, const int* __restrict__ s1,
  const int* __restrict__ s2, const int* __restrict__ s3, const float* __restrict__ E,
  u16* __restrict__ xh, u16* __restrict__ xl)
{
  int id = blockIdx.x*256 + threadIdx.x;     // 204800 = 4*6400*8
  int e8 = id & 7;
  int rm = id >> 3;                          // m*6400 + r
  int m = rm / 6400; int r = rm - m*6400;
  int t = r >> 7, b = r & 127;
  const int* sq = (m==0)? s0 : (m==1)? s1 : (m==2)? s2 : s3;
  int idx = sq[b*T_ + t];
  float sc = (idx==0)? 0.0f : 1.0f;
  const float4* ep = (const float4*)(E + (size_t)idx*64 + e8*8);
  float4 v0 = ep[0], v1 = ep[1];
  float vals[8] = {v0.x,v0.y,v0.z,v0.w,v1.x,v1.y,v1.z,v1.w};
  u32 hw[4], lw[4];
  #pragma unroll
  for (int q=0;q<4;q++){
    float f0 = vals[2*q]*sc, f1 = vals[2*q+1]*sc;
    u16 h0 = f2bf(f0), h1 = f2bf(f1);
    u16 l0 = f2bf(f0 - bf2f(h0)), l1 = f2bf(f1 - bf2f(h1));
    hw[q] = (u32)h0 | ((u32)h1<<16);
    lw[q] = (u32)l0 | ((u32)l1<<16);
  }
  size_t off = (size_t)rm*64 + e8*8;
  uint4 hv; hv.x=hw[0]; hv.y=hw[1]; hv.z=hw[2]; hv.w=hw[3];
  uint4 lv; lv.x=lw[0]; lv.y=lw[1]; lv.z=lw[2]; lv.w=lw[3];
  *(uint4*)(xh + off) = hv;
  *(uint4*)(xl + off) = lv;
}

// ---------------- prep W: transpose Wx[m][d][g] -> [m][g][d], split bf16 hi/lo ----------------
__global__ __launch_bounds__(256) void k_prep_w(const float* __restrict__ Wx,
  u16* __restrict__ wh, u16* __restrict__ wl)
{
  __shared__ float tl[64][65];
  int m = blockIdx.x / 48, gt = blockIdx.x % 48;
  for (int it=0; it<16; ++it){
    int li = threadIdx.x + it*256;
    int dl = li >> 6, gl = li & 63;
    tl[dl][gl] = Wx[((size_t)m*64 + dl)*3072 + gt*64 + gl];
  }
  __syncthreads();
  for (int it=0; it<2; ++it){
    int unit = threadIdx.x + it*256;          // 512 units: gl*8 + d8
    int gl = unit >> 3, d8 = unit & 7;
    u32 hw[4], lw[4];
    #pragma unroll
    for (int q=0;q<4;q++){
      float f0 = tl[d8*8+2*q][gl], f1 = tl[d8*8+2*q+1][gl];
      u16 h0 = f2bf(f0), h1 = f2bf(f1);
      u16 l0 = f2bf(f0 - bf2f(h0)), l1 = f2bf(f1 - bf2f(h1));
      hw[q] = (u32)h0 | ((u32)h1<<16);
      lw[q] = (u32)l0 | ((u32)l1<<16);
    }
    size_t off = ((size_t)m*3072 + gt*64 + gl)*64 + d8*8;
    uint4 hv; hv.x=hw[0]; hv.y=hw[1]; hv.z=hw[2]; hv.w=hw[3];
    uint4 lv; lv.x=lw[0]; lv.y=lw[1]; lv.z=lw[2]; lv.w=lw[3];
    *(uint4*)(wh + off) = hv;
    *(uint4*)(wl + off) = lv;
  }
}

// ---------------- gi GEMM via MFMA (split-bf16) ----------------
__global__ __launch_bounds__(256) void k_gemm_gi(const u16* __restrict__ xh, const u16* __restrict__ xl,
  const u16* __restrict__ wh, const u16* __restrict__ wl,
  const float* __restrict__ bx, const float* __restrict__ bhp, u16* __restrict__ gi)
{
  int bi = blockIdx.x;
  int q4 = bi & 3; int k = (bi>>2)&63; int m = bi>>8;
  int wv = threadIdx.x>>6, lane = threadIdx.x&63;
  int n16 = lane & 15, quad = lane >> 4;

  short8 Ah[3][2], Al[3][2];
  #pragma unroll
  for (int gate=0; gate<3; ++gate){
    int g = gate*1024 + k*16 + n16;
    #pragma unroll
    for (int c=0; c<2; ++c){
      size_t aoff = ((size_t)(m*3072 + g))*64 + c*32 + quad*8;
      Ah[gate][c] = *(const short8*)(wh + aoff);
      Al[gate][c] = *(const short8*)(wl + aoff);
    }
  }
  float bias[3][4];
  #pragma unroll
  for (int gate=0; gate<3; ++gate){
    #pragma unroll
    for (int rg=0; rg<4; ++rg){
      int j = quad*4 + rg;
      int g = gate*1024 + k*16 + j;
      bias[gate][rg] = bx[m*3072 + g] + ((gate<2)? bhp[(m*64+k)*48 + gate*16 + j] : 0.0f);
    }
  }
  for (int i=0; i<25; ++i){
    int row = q4*1600 + (i*4+wv)*16 + n16;
    size_t xoff = ((size_t)(m*6400 + row))*64 + quad*8;
    short8 Bh0 = *(const short8*)(xh + xoff);
    short8 Bh1 = *(const short8*)(xh + xoff + 32);
    short8 Bl0 = *(const short8*)(xl + xoff);
    short8 Bl1 = *(const short8*)(xl + xoff + 32);
    #pragma unroll
    for (int gate=0; gate<3; ++gate){
      f32x4 acc = {bias[gate][0], bias[gate][1], bias[gate][2], bias[gate][3]};
      acc = __builtin_amdgcn_mfma_f32_16x16x32_bf16(Ah[gate][0], Bh0, acc, 0,0,0);
      acc = __builtin_amdgcn_mfma_f32_16x16x32_bf16(Ah[gate][1], Bh1, acc, 0,0,0);
      acc = __builtin_amdgcn_mfma_f32_16x16x32_bf16(Al[gate][0], Bh0, acc, 0,0,0);
      acc = __builtin_amdgcn_mfma_f32_16x16x32_bf16(Al[gate][1], Bh1, acc, 0,0,0);
      acc = __builtin_amdgcn_mfma_f32_16x16x32_bf16(Ah[gate][0], Bl0, acc, 0,0,0);
      acc = __builtin_amdgcn_mfma_f32_16x16x32_bf16(Ah[gate][1], Bl1, acc, 0,0,0);
      u32 w0 = (u32)f2bf(acc[0]) | ((u32)f2bf(acc[1])<<16);
      u32 w1 = (u32)f2bf(acc[2]) | ((u32)f2bf(acc[3])<<16);
      size_t go = ((size_t)((m*64+k)*6400 + row))*48 + gate*16 + quad*4;
      uint2 st; st.x = w0; st.y = w1;
      *(uint2*)(gi + go) = st;
    }
  }
}

// ---------------- GRU scan: 16 lanes per (b,m,k) chain ----------------
template<int RC, int WN, int FOLD>
__global__ __launch_bounds__(256,4) void k_gru(u16* __restrict__ gi, const float* __restrict__ Wh,
  const float* __restrict__ bhp, const float* __restrict__ rp,
  u16* __restrict__ Nbuf, float* __restrict__ behE)
{
  __shared__ float hbuf[256];
  int tid = threadIdx.x;
  int wave = tid>>6, lane = tid&63;
  int bg = lane>>4, j = lane&15;
  int bi = blockIdx.x;
  int bblk = bi & 7; bi >>= 3;
  int k = bi & 63; int m = bi >> 6;
  int b = bblk*16 + wave*4 + bg;
  float wr[16], wz[16], wn[16];
  const float* whp = Wh + ((size_t)(m*64+k)*16)*48;
  #pragma unroll
  for (int l=0;l<16;l++){
    wr[l] = whp[l*48 + j];
    wz[l] = whp[l*48 + 16 + j];
    wn[l] = whp[l*48 + 32 + j];
  }
  float bhn = bhp[(m*64+k)*48 + 32 + j];
  float rv = 0.f;
  if (RC) rv = rp[((size_t)b*64+k)*16 + j];
  float hown = 0.0f;
  hbuf[tid] = 0.0f;
  __builtin_amdgcn_wave_barrier();
  int gBase = (((m*64+k)*50)*128 + b)*48 + j;
  int nBase = (((m*64+k)*50)*128 + b)*16 + j;
  const float* hgrp = &hbuf[tid & ~15];
  for (int t=0;t<50;++t){
    float gir = bf2f(gi[gBase]);
    float giz = bf2f(gi[gBase+16]);
    float gin = bf2f(gi[gBase+32]);
    float Ct = 0.0f;
    if (RC) Ct = bf2f(Nbuf[nBase]) * rv;
    if (FOLD) gi[gBase+16] = f2bf(giz + Ct);
    float hv[16];
    *(float4*)&hv[0]  = ((const float4*)hgrp)[0];
    *(float4*)&hv[4]  = ((const float4*)hgrp)[1];
    *(float4*)&hv[8]  = ((const float4*)hgrp)[2];
    *(float4*)&hv[12] = ((const float4*)hgrp)[3];
    float ghr = 0.f, ghz = 0.f, ghn = bhn;
    #pragma unroll
    for (int l=0;l<16;l++){ ghr += hv[l]*wr[l]; ghz += hv[l]*wz[l]; ghn += hv[l]*wn[l]; }
    float rg = fsig(gir + ghr);
    float zg = fsig(giz + ghz + Ct);
    float ng = ftanh(gin + rg*ghn);
    float hn = ng + zg*(hown - ng);
    if (WN) Nbuf[nBase] = f2bf(ng);
    hown = hn;
    __builtin_amdgcn_wave_barrier();
    hbuf[tid] = hn;
    __builtin_amdgcn_wave_barrier();
    gBase += 128*48;
    nBase += 128*16;
  }
  behE[(((size_t)b*64 + k)*4 + m)*16 + j] = hown;
}

// ---------------- softmax(b)+v+v_ with on-the-fly u recompute ----------------
__global__ __launch_bounds__(256) void k_cv(const float* __restrict__ bmat, const float* __restrict__ behE,
  const float* __restrict__ W, const float* __restrict__ alpha, const float* __restrict__ wv,
  const float* __restrict__ bias, float* __restrict__ vout, float* __restrict__ vT)
{
  __shared__ float cm[64][65];
  __shared__ float vsh[64][17];
  __shared__ float besh[4096];
  int b = blockIdx.x, tid = threadIdx.x;
  for (int it=0; it<16; ++it){
    int li = tid + it*256;
    cm[li>>6][li&63] = bmat[(size_t)b*4096 + li];
    besh[li] = behE[(size_t)b*4096 + li];
  }
  __syncthreads();
  if (tid < 64){
    float mx = -1e30f;
    for (int jj=0;jj<64;jj++) mx = fmaxf(mx, cm[tid][jj]);
    float sm = 0.f;
    for (int jj=0;jj<64;jj++){ float e = fexp(cm[tid][jj]-mx); cm[tid][jj]=e; sm+=e; }
    float inv = 1.0f/sm;
    for (int jj=0;jj<64;jj++) cm[tid][jj] *= inv;
  }
  __syncthreads();
  int j = tid & 63, dq = tid>>6;
  float a0=0,a1=0,a2=0,a3=0;
  for (int i=0;i<64;++i){
    float cij = cm[i][j];
    #pragma unroll
    for (int q=0;q<4;++q){
      int d = dq*4+q;
      const float* wp = W + ((size_t)((i*16+d)*4))*64 + j;
      float uu = besh[i*64+d]*wp[0] + besh[i*64+16+d]*wp[64]
               + besh[i*64+32+d]*wp[128] + besh[i*64+48+d]*wp[192];
      float cu = cij*uu;
      if (q==0) a0 += cu; else if (q==1) a1 += cu; else if (q==2) a2 += cu; else a3 += cu;
    }
  }
  float al = alpha[0];
  a0*=al; a1*=al; a2*=al; a3*=al;
  vsh[j][dq*4]=a0; vsh[j][dq*4+1]=a1; vsh[j][dq*4+2]=a2; vsh[j][dq*4+3]=a3;
  float* vp = vout + ((size_t)b*64 + j)*16 + dq*4;
  vp[0]=a0; vp[1]=a1; vp[2]=a2; vp[3]=a3;
  __syncthreads();
  if (tid < 64){
    float s=0.f;
    #pragma unroll
    for (int dd=0; dd<16; ++dd){ float q = vsh[tid][dd]; s += q*q; }
    vT[tid*128 + b] = sqrtf(s)*wv[tid] + bias[tid];
  }
}

// ---------------- fused logits+softmax+p partials, LDS-staged E tiles, atomic buckets ----------------
__global__ __launch_bounds__(256,3) void k_pfused(const float* __restrict__ vT, const float* __restrict__ E,
  float* __restrict__ partial)
{
  __shared__ float et[64*64];
  __shared__ float pb[128][66];
  __shared__ float sb[2][128];
  int tid = threadIdx.x, lane = tid&63, w = tid>>6;
  int bh = w & 1, ih = w >> 1;
  int b = bh*64 + lane;
  float vr[64];
  #pragma unroll
  for (int kk=0;kk<64;kk++) vr[kk] = vT[kk*128 + b];
  float acc[64];
  #pragma unroll
  for (int q=0;q<64;q++) acc[q]=0.f;
  float srun = 0.f;
  int start = blockIdx.x*CHUNK2;
  for (int sub=0; sub<3; ++sub){
    int i0 = start + sub*64;
    __syncthreads();
    #pragma unroll
    for (int it=0; it<4; ++it){
      int li = tid + it*256;              // 1024 float4 slots
      int item = li >> 4, d4 = li & 15;
      int gidx = i0 + item;
      float4 val = {0.f,0.f,0.f,0.f};
      if (gidx < NIT) val = ((const float4*)E)[(size_t)gidx*16 + d4];
      ((float4*)et)[item*16 + d4] = val;
    }
    __syncthreads();
    for (int t2=0; t2<32; ++t2){
      int item = ih*32 + t2;
      if (i0 + item >= NIT) break;
      const float4* ep = (const float4*)(et + item*64);
      float s0=0,s1=0,s2=0,s3=0;
      #pragma unroll
      for (int q=0;q<16;q++){
        float4 e = ep[q];
        s0 += e.x*vr[4*q]; s1 += e.y*vr[4*q+1]; s2 += e.z*vr[4*q+2]; s3 += e.w*vr[4*q+3];
      }
      float ex = fexp((s0+s1)+(s2+s3));
      srun += ex;
      #pragma unroll
      for (int q=0;q<16;q++){
        float4 e = ep[q];
        acc[4*q+0] += ex*e.x; acc[4*q+1] += ex*e.y; acc[4*q+2] += ex*e.z; acc[4*q+3] += ex*e.w;
      }
    }
  }
  __syncthreads();
  if (ih == 0){
    #pragma unroll
    for (int q=0;q<64;q++) pb[b][q] = acc[q];
    sb[0][b] = srun;
  }
  __syncthreads();
  if (ih == 1){
    #pragma unroll
    for (int q=0;q<64;q++) pb[b][q] += acc[q];
    sb[1][b] = srun;
  }
  __syncthreads();
  float* dst = partial + (size_t)(blockIdx.x & (NBUCKET-1))*8448;
  for (int it=0; it<33; ++it){
    int li = tid + it*256;                 // 8448 slots, use 65 of 66 per batch
    int bb = li/66, cc = li%66;
    if (cc < 64)      atomicAdd(dst+li, pb[bb][cc]);
    else if (cc == 64) atomicAdd(dst+li, sb[0][bb]+sb[1][bb]);
  }
}

__global__ __launch_bounds__(256) void k_pcomb(const float* __restrict__ partial, float* __restrict__ p)
{
  int id = blockIdx.x*256 + threadIdx.x;   // b*64+d
  int b = id>>6, d = id&63;
  float a = 0.f, s = 0.f;
  #pragma unroll
  for (int q=0;q<NBUCKET;q++){
    const float* pp = partial + (size_t)q*8448 + b*66;
    a += pp[d]; s += pp[64];
  }
  p[id] = a/s;
}

// ---------------- r[b][j][l] = sum_d cat(p,v)[b,j,d]*Wc[j][d][l] ----------------
__global__ __launch_bounds__(256) void k_r(const float* __restrict__ p, const float* __restrict__ v,
  const float* __restrict__ Wc, float* __restrict__ r, float* __restrict__ rT)
{
  int gid = blockIdx.x*256 + threadIdx.x;
  int l = gid & 15, j = (gid>>4)&63, b = gid>>10;
  const float* wc = Wc + ((size_t)j*80)*16 + l;
  const float* pbp = p + b*64;
  float acc = 0.f;
  #pragma unroll 8
  for (int d=0; d<64; ++d) acc += pbp[d]*wc[d*16];
  const float* vb = v + ((size_t)b*64 + j)*16;
  #pragma unroll
  for (int d=0; d<16; ++d) acc += vb[d]*wc[(64+d)*16];
  r[((size_t)b*64+j)*16 + l] = acc;
  rT[((size_t)b*16+l)*64 + j] = acc;
}

// ---------------- b[b][i][j] += sum_d u[b][i][d][j]*r[b][j][d], u recomputed ----------------
__global__ __launch_bounds__(256) void k_bupd(const float* __restrict__ behE, const float* __restrict__ W,
  const float* __restrict__ rT, float* __restrict__ bmat)
{
  int lane = threadIdx.x & 63;
  int idx = blockIdx.x*4 + (threadIdx.x>>6);   // b*64+i
  int b = idx >> 6, i = idx & 63;
  const float* be = behE + (size_t)idx*64;
  const float* rp = rT + (size_t)b*1024;
  float acc = 0.f;
  #pragma unroll
  for (int d=0; d<16; ++d){
    const float* wp = W + ((size_t)((i*16+d)*4))*64 + lane;
    float uu = be[d]*wp[0] + be[16+d]*wp[64] + be[32+d]*wp[128] + be[48+d]*wp[192];
    acc += uu * rp[d*64 + lane];
  }
  bmat[(size_t)idx*64 + lane] += acc;
}

// ---------------- logits[b][i] = sum_k vT[k][b]*E[i][k] ----------------
__global__ __launch_bounds__(128) void k_logits(const float* __restrict__ vT, const float* __restrict__ E,
  float* __restrict__ out, int ld, int storeW)
{
  __shared__ float tile[128][33];
  int tid = threadIdx.x, lane = tid & 63, bh2 = tid>>6;
  int b = bh2*64 + lane;
  float vr[64];
  #pragma unroll
  for (int kk=0;kk<64;kk++) vr[kk] = vT[kk*128 + b];
  int i0 = blockIdx.x*32;
  for (int ii=0; ii<32; ++ii){
    int i = i0 + ii;
    float acc = 0.0f;
    if (i < NIT){
      const float4* er = (const float4*)(E + (size_t)i*64);
      float s0=0,s1=0,s2=0,s3=0;
      #pragma unroll
      for (int q=0;q<16;q++){
        float4 e = er[q];
        s0 += e.x*vr[4*q]; s1 += e.y*vr[4*q+1]; s2 += e.z*vr[4*q+2]; s3 += e.w*vr[4*q+3];
      }
      acc = (s0+s1)+(s2+s3);
    }
    tile[b][ii] = acc;
  }
  __syncthreads();
  int nv = storeW - i0; if (nv > 32) nv = 32; if (nv < 0) nv = 0;
  float* op = out + (size_t)tid*ld + i0;
  for (int ii=0; ii<nv; ++ii) op[ii] = tile[tid][ii];
}

extern "C" void kernel_launch(void* const* d_in, const int* in_sizes, int n_in,
                              void* d_out, int out_size, void* d_ws, size_t ws_size,
                              hipStream_t stream)
{
  (void)in_sizes; (void)n_in; (void)out_size; (void)ws_size;
  const int*   s0 = (const int*)d_in[0];
  const int*   s1 = (const int*)d_in[1];
  const int*   s2 = (const int*)d_in[2];
  const int*   s3 = (const int*)d_in[3];
  const float* E  = (const float*)d_in[4];
  const float* W  = (const float*)d_in[5];
  const float* Wc = (const float*)d_in[6];
  const float* alpha = (const float*)d_in[7];
  const float* wv    = (const float*)d_in[8];
  const float* bias  = (const float*)d_in[9];
  const float* Wx = (const float*)d_in[10];
  const float* bx = (const float*)d_in[11];
  const float* Wh = (const float*)d_in[12];
  const float* bh = (const float*)d_in[13];

  char* ws = (char*)d_ws;
  size_t off = 0;
  auto alloc = [&](size_t bytes)->void*{ void* q = ws + off; off += (bytes + 255) & ~(size_t)255; return q; };
  u16*   gi   = (u16*)  alloc((size_t)M_*K_*T_*B_*48*2);   // 157.3 MB
  u16*   N1   = (u16*)  alloc((size_t)M_*K_*T_*B_*16*2);   // 52.4 MB
  u16*   xh   = (u16*)  alloc((size_t)M_*6400*64*2);
  u16*   xl   = (u16*)  alloc((size_t)M_*6400*64*2);
  u16*   wh   = (u16*)  alloc((size_t)M_*3072*64*2);
  u16*   wl   = (u16*)  alloc((size_t)M_*3072*64*2);
  float* bmat = (float*)alloc((size_t)B_*64*64*4);
  float* behE = (float*)alloc((size_t)B_*64*4*16*4);
  float* v    = (float*)alloc((size_t)B_*64*16*4);
  float* vT   = (float*)alloc((size_t)64*128*4);
  float* r1   = (float*)alloc((size_t)B_*64*16*4);
  float* rT1  = (float*)alloc((size_t)B_*64*16*4);
  float* r2   = (float*)alloc((size_t)B_*64*16*4);
  float* rT2  = (float*)alloc((size_t)B_*64*16*4);
  float* p    = (float*)alloc((size_t)B_*64*4);
  float* partial = (float*)alloc((size_t)NBUCKET*8448*4); // 270 KB
  // total ~227 MB

  hipMemsetAsync(bmat, 0, (size_t)B_*64*64*4, stream);
  k_prep_x<<<800,256,0,stream>>>(s0,s1,s2,s3,E,xh,xl);
  k_prep_w<<<192,256,0,stream>>>(Wx,wh,wl);
  k_gemm_gi<<<1024,256,0,stream>>>(xh,xl,wh,wl,bx,bh,gi);

  // ---- routing iteration 1 ----
  k_gru<0,1,0><<<2048,256,0,stream>>>(gi,Wh,bh,nullptr,N1,behE);
  k_cv<<<128,256,0,stream>>>(bmat,behE,W,alpha,wv,bias,v,vT);
  hipMemsetAsync(partial, 0, (size_t)NBUCKET*8448*4, stream);
  k_pfused<<<NBP2,256,0,stream>>>(vT,E,partial);
  k_pcomb<<<32,256,0,stream>>>(partial,p);
  k_r<<<512,256,0,stream>>>(p,v,Wc,r1,rT1);
  k_bupd<<<2048,256,0,stream>>>(behE,W,rT1,bmat);

  // ---- routing iteration 2: reads C1=N1*r1 live, folds into gi.z, overwrites N with n2 ----
  k_gru<1,1,1><<<2048,256,0,stream>>>(gi,Wh,bh,r1,N1,behE);
  k_cv<<<128,256,0,stream>>>(bmat,behE,W,alpha,wv,bias,v,vT);
  hipMemsetAsync(partial, 0, (size_t)NBUCKET*8448*4, stream);
  k_pfused<<<NBP2,256,0,stream>>>(vT,E,partial);
  k_pcomb<<<32,256,0,stream>>>(partial,p);
  k_r<<<512,256,0,stream>>>(p,v,Wc,r2,rT2);
  k_bupd<<<2048,256,0,stream>>>(behE,W,rT2,bmat);

  // ---- final pass: C = (folded C1) + N2*r2 live ----
  k_gru<1,0,0><<<2048,256,0,stream>>>(gi,Wh,bh,r2,N1,behE);
  k_cv<<<128,256,0,stream>>>(bmat,behE,W,alpha,wv,bias,v,vT);
  k_logits<<<3126,128,0,stream>>>(vT,E,(float*)d_out,NIT,NIT);
}

// Round 5
// 849.281 us; speedup vs baseline: 1.7164x; 1.2098x over previous
//
#include <hip/hip_runtime.h>
#include <hip/hip_bf16.h>
#include <cstdint>
#include <cstddef>

#define B_   128
#define T_   50
#define M_   4
#define D_   64
#define K_   64
#define L_   16
#define NIT  100001
#define NBP2 521
#define CHUNK2 192     /* 521*192 = 100032 >= NIT */
#define NBUCKET 8

typedef unsigned short u16;
typedef unsigned int   u32;
typedef __attribute__((ext_vector_type(8))) short short8;
typedef __attribute__((ext_vector_type(4))) float f32x4;

__device__ __forceinline__ float bf2f(u16 v){ u32 u = ((u32)v)<<16; float f; __builtin_memcpy(&f,&u,4); return f; }
__device__ __forceinline__ u16 f2bf(float f){
  u32 u; __builtin_memcpy(&u,&f,4);
  u32 r = (u + 0x7FFFu + ((u>>16)&1u)) >> 16;
  return (u16)r;
}
__device__ __forceinline__ float fexp(float x){ return __builtin_amdgcn_exp2f(x*1.4426950408889634f); }
__device__ __forceinline__ float fsig(float x){ return __builtin_amdgcn_rcpf(1.0f + fexp(-x)); }
__device__ __forceinline__ float ftanh(float x){ return 1.0f - 2.0f*__builtin_amdgcn_rcpf(1.0f + fexp(2.0f*x)); }

// ---------------- prep x: embed+mask, split fp32 -> bf16 hi/lo, layout [m][t*128+b][64] ----------------
__global__ __launch_bounds__(256) void k_prep_x(const int* __restrict__ s0, const int* __restrict__ s1,
  const int* __restrict__ s2, const int* __restrict__ s3, const float* __restrict__ E,
  u16* __restrict__ xh, u16* __restrict__ xl)
{
  int id = blockIdx.x*256 + threadIdx.x;     // 204800 = 4*6400*8
  int e8 = id & 7;
  int rm = id >> 3;                          // m*6400 + r
  int m = rm / 6400; int r = rm - m*6400;
  int t = r >> 7, b = r & 127;
  const int* sq = (m==0)? s0 : (m==1)? s1 : (m==2)? s2 : s3;
  int idx = sq[b*T_ + t];
  float sc = (idx==0)? 0.0f : 1.0f;
  const float4* ep = (const float4*)(E + (size_t)idx*64 + e8*8);
  float4 v0 = ep[0], v1 = ep[1];
  float vals[8] = {v0.x,v0.y,v0.z,v0.w,v1.x,v1.y,v1.z,v1.w};
  u32 hw[4], lw[4];
  #pragma unroll
  for (int q=0;q<4;q++){
    float f0 = vals[2*q]*sc, f1 = vals[2*q+1]*sc;
    u16 h0 = f2bf(f0), h1 = f2bf(f1);
    u16 l0 = f2bf(f0 - bf2f(h0)), l1 = f2bf(f1 - bf2f(h1));
    hw[q] = (u32)h0 | ((u32)h1<<16);
    lw[q] = (u32)l0 | ((u32)l1<<16);
  }
  size_t off = (size_t)rm*64 + e8*8;
  uint4 hv; hv.x=hw[0]; hv.y=hw[1]; hv.z=hw[2]; hv.w=hw[3];
  uint4 lv; lv.x=lw[0]; lv.y=lw[1]; lv.z=lw[2]; lv.w=lw[3];
  *(uint4*)(xh + off) = hv;
  *(uint4*)(xl + off) = lv;
}

// ---------------- prep W: transpose Wx[m][d][g] -> [m][g][d], split bf16 hi/lo ----------------
__global__ __launch_bounds__(256) void k_prep_w(const float* __restrict__ Wx,
  u16* __restrict__ wh, u16* __restrict__ wl)
{
  __shared__ float tl[64][65];
  int m = blockIdx.x / 48, gt = blockIdx.x % 48;
  for (int it=0; it<16; ++it){
    int li = threadIdx.x + it*256;
    int dl = li >> 6, gl = li & 63;
    tl[dl][gl] = Wx[((size_t)m*64 + dl)*3072 + gt*64 + gl];
  }
  __syncthreads();
  for (int it=0; it<2; ++it){
    int unit = threadIdx.x + it*256;          // 512 units: gl*8 + d8
    int gl = unit >> 3, d8 = unit & 7;
    u32 hw[4], lw[4];
    #pragma unroll
    for (int q=0;q<4;q++){
      float f0 = tl[d8*8+2*q][gl], f1 = tl[d8*8+2*q+1][gl];
      u16 h0 = f2bf(f0), h1 = f2bf(f1);
      u16 l0 = f2bf(f0 - bf2f(h0)), l1 = f2bf(f1 - bf2f(h1));
      hw[q] = (u32)h0 | ((u32)h1<<16);
      lw[q] = (u32)l0 | ((u32)l1<<16);
    }
    size_t off = ((size_t)m*3072 + gt*64 + gl)*64 + d8*8;
    uint4 hv; hv.x=hw[0]; hv.y=hw[1]; hv.z=hw[2]; hv.w=hw[3];
    uint4 lv; lv.x=lw[0]; lv.y=lw[1]; lv.z=lw[2]; lv.w=lw[3];
    *(uint4*)(wh + off) = hv;
    *(uint4*)(wl + off) = lv;
  }
}

// ---------------- gi GEMM via MFMA (split-bf16), gate-plane output layout ----------------
// gi[m][k][gate][t*128+b][16]
__global__ __launch_bounds__(256) void k_gemm_gi(const u16* __restrict__ xh, const u16* __restrict__ xl,
  const u16* __restrict__ wh, const u16* __restrict__ wl,
  const float* __restrict__ bx, const float* __restrict__ bhp, u16* __restrict__ gi)
{
  int bi = blockIdx.x;
  int q4 = bi & 3; int k = (bi>>2)&63; int m = bi>>8;
  int wv = threadIdx.x>>6, lane = threadIdx.x&63;
  int n16 = lane & 15, quad = lane >> 4;

  short8 Ah[3][2], Al[3][2];
  #pragma unroll
  for (int gate=0; gate<3; ++gate){
    int g = gate*1024 + k*16 + n16;
    #pragma unroll
    for (int c=0; c<2; ++c){
      size_t aoff = ((size_t)(m*3072 + g))*64 + c*32 + quad*8;
      Ah[gate][c] = *(const short8*)(wh + aoff);
      Al[gate][c] = *(const short8*)(wl + aoff);
    }
  }
  float bias[3][4];
  #pragma unroll
  for (int gate=0; gate<3; ++gate){
    #pragma unroll
    for (int rg=0; rg<4; ++rg){
      int j = quad*4 + rg;
      int g = gate*1024 + k*16 + j;
      bias[gate][rg] = bx[m*3072 + g] + ((gate<2)? bhp[(m*64+k)*48 + gate*16 + j] : 0.0f);
    }
  }
  for (int i=0; i<25; ++i){
    int row = q4*1600 + (i*4+wv)*16 + n16;
    size_t xoff = ((size_t)(m*6400 + row))*64 + quad*8;
    short8 Bh0 = *(const short8*)(xh + xoff);
    short8 Bh1 = *(const short8*)(xh + xoff + 32);
    short8 Bl0 = *(const short8*)(xl + xoff);
    short8 Bl1 = *(const short8*)(xl + xoff + 32);
    #pragma unroll
    for (int gate=0; gate<3; ++gate){
      f32x4 acc = {bias[gate][0], bias[gate][1], bias[gate][2], bias[gate][3]};
      acc = __builtin_amdgcn_mfma_f32_16x16x32_bf16(Ah[gate][0], Bh0, acc, 0,0,0);
      acc = __builtin_amdgcn_mfma_f32_16x16x32_bf16(Ah[gate][1], Bh1, acc, 0,0,0);
      acc = __builtin_amdgcn_mfma_f32_16x16x32_bf16(Al[gate][0], Bh0, acc, 0,0,0);
      acc = __builtin_amdgcn_mfma_f32_16x16x32_bf16(Al[gate][1], Bh1, acc, 0,0,0);
      acc = __builtin_amdgcn_mfma_f32_16x16x32_bf16(Ah[gate][0], Bl0, acc, 0,0,0);
      acc = __builtin_amdgcn_mfma_f32_16x16x32_bf16(Ah[gate][1], Bl1, acc, 0,0,0);
      u32 w0 = (u32)f2bf(acc[0]) | ((u32)f2bf(acc[1])<<16);
      u32 w1 = (u32)f2bf(acc[2]) | ((u32)f2bf(acc[3])<<16);
      size_t go = (((size_t)(m*64+k)*3 + gate)*6400 + row)*16 + quad*4;
      uint2 st; st.x = w0; st.y = w1;
      *(uint2*)(gi + go) = st;
    }
  }
}

// ---------------- GRU scan: 16 lanes per (b,m,k) chain; plane layout + t+1 register prefetch ----------------
template<int RC, int WN, int FOLD>
__global__ __launch_bounds__(256,4) void k_gru(u16* __restrict__ gi, const float* __restrict__ Wh,
  const float* __restrict__ bhp, const float* __restrict__ rp,
  u16* __restrict__ Nbuf, float* __restrict__ behE)
{
  __shared__ float hbuf[256];
  int tid = threadIdx.x;
  int wave = tid>>6, lane = tid&63;
  int bg = lane>>4, j = lane&15;
  int bi = blockIdx.x;
  int bblk = bi & 7; bi >>= 3;
  int k = bi & 63; int m = bi >> 6;
  int b = bblk*16 + wave*4 + bg;
  float wr[16], wz[16], wn[16];
  const float* whp = Wh + ((size_t)(m*64+k)*16)*48;
  #pragma unroll
  for (int l=0;l<16;l++){
    wr[l] = whp[l*48 + j];
    wz[l] = whp[l*48 + 16 + j];
    wn[l] = whp[l*48 + 32 + j];
  }
  float bhn = bhp[(m*64+k)*48 + 32 + j];
  float rv = 0.f;
  if (RC) rv = rp[((size_t)b*64+k)*16 + j];
  float hown = 0.0f;
  hbuf[tid] = 0.0f;
  __builtin_amdgcn_wave_barrier();
  size_t pbase = ((size_t)(m*64+k)*3)*102400 + b*16 + j;   // 102400 = 6400*16
  const u16* gR = gi + pbase;
  u16*       gZ = gi + pbase + 102400;
  const u16* gN = gi + pbase + 204800;
  u16*       nP = Nbuf + ((size_t)(m*64+k))*102400 + b*16 + j;
  const float* hgrp = &hbuf[tid & ~15];
  float gir_c = bf2f(gR[0]);
  float giz_c = bf2f(gZ[0]);
  float gin_c = bf2f(gN[0]);
  float Nc = 0.f;
  if (RC) Nc = bf2f(nP[0]);
  for (int t=0;t<50;++t){
    float gir_n=0.f, giz_n=0.f, gin_n=0.f, Nn=0.f;
    if (t<49){
      int nxt = (t+1)*2048;                 // 128*16 elements per step
      gir_n = bf2f(gR[nxt]);
      giz_n = bf2f(gZ[nxt]);
      gin_n = bf2f(gN[nxt]);
      if (RC) Nn = bf2f(nP[nxt]);
    }
    float Ct = 0.0f;
    if (RC) Ct = Nc * rv;
    if (FOLD) gZ[t*2048] = f2bf(giz_c + Ct);
    float hv[16];
    *(float4*)&hv[0]  = ((const float4*)hgrp)[0];
    *(float4*)&hv[4]  = ((const float4*)hgrp)[1];
    *(float4*)&hv[8]  = ((const float4*)hgrp)[2];
    *(float4*)&hv[12] = ((const float4*)hgrp)[3];
    float ghr = 0.f, ghz = 0.f, ghn = bhn;
    #pragma unroll
    for (int l=0;l<16;l++){ ghr += hv[l]*wr[l]; ghz += hv[l]*wz[l]; ghn += hv[l]*wn[l]; }
    float rg = fsig(gir_c + ghr);
    float zg = fsig(giz_c + ghz + Ct);
    float ng = ftanh(gin_c + rg*ghn);
    float hn = ng + zg*(hown - ng);
    if (WN) nP[t*2048] = f2bf(ng);
    hown = hn;
    __builtin_amdgcn_wave_barrier();
    hbuf[tid] = hn;
    __builtin_amdgcn_wave_barrier();
    gir_c=gir_n; giz_c=giz_n; gin_c=gin_n; Nc=Nn;
  }
  behE[(((size_t)b*64 + k)*4 + m)*16 + j] = hown;
}

// ---------------- softmax(b)+v+v_ with on-the-fly u recompute ----------------
__global__ __launch_bounds__(256) void k_cv(const float* __restrict__ bmat, const float* __restrict__ behE,
  const float* __restrict__ W, const float* __restrict__ alpha, const float* __restrict__ wv,
  const float* __restrict__ bias, float* __restrict__ vout, float* __restrict__ vT)
{
  __shared__ float cm[64][65];
  __shared__ float vsh[64][17];
  __shared__ float besh[4096];
  int b = blockIdx.x, tid = threadIdx.x;
  for (int it=0; it<16; ++it){
    int li = tid + it*256;
    cm[li>>6][li&63] = bmat[(size_t)b*4096 + li];
    besh[li] = behE[(size_t)b*4096 + li];
  }
  __syncthreads();
  if (tid < 64){
    float mx = -1e30f;
    for (int jj=0;jj<64;jj++) mx = fmaxf(mx, cm[tid][jj]);
    float sm = 0.f;
    for (int jj=0;jj<64;jj++){ float e = fexp(cm[tid][jj]-mx); cm[tid][jj]=e; sm+=e; }
    float inv = 1.0f/sm;
    for (int jj=0;jj<64;jj++) cm[tid][jj] *= inv;
  }
  __syncthreads();
  int j = tid & 63, dq = tid>>6;
  float a0=0,a1=0,a2=0,a3=0;
  for (int i=0;i<64;++i){
    float cij = cm[i][j];
    #pragma unroll
    for (int q=0;q<4;++q){
      int d = dq*4+q;
      const float* wp = W + ((size_t)((i*16+d)*4))*64 + j;
      float uu = besh[i*64+d]*wp[0] + besh[i*64+16+d]*wp[64]
               + besh[i*64+32+d]*wp[128] + besh[i*64+48+d]*wp[192];
      float cu = cij*uu;
      if (q==0) a0 += cu; else if (q==1) a1 += cu; else if (q==2) a2 += cu; else a3 += cu;
    }
  }
  float al = alpha[0];
  a0*=al; a1*=al; a2*=al; a3*=al;
  vsh[j][dq*4]=a0; vsh[j][dq*4+1]=a1; vsh[j][dq*4+2]=a2; vsh[j][dq*4+3]=a3;
  float* vp = vout + ((size_t)b*64 + j)*16 + dq*4;
  vp[0]=a0; vp[1]=a1; vp[2]=a2; vp[3]=a3;
  __syncthreads();
  if (tid < 64){
    float s=0.f;
    #pragma unroll
    for (int dd=0; dd<16; ++dd){ float q = vsh[tid][dd]; s += q*q; }
    vT[tid*128 + b] = sqrtf(s)*wv[tid] + bias[tid];
  }
}

// ---------------- fused logits+softmax+p partials, LDS-staged E tiles, atomic buckets ----------------
__global__ __launch_bounds__(256,3) void k_pfused(const float* __restrict__ vT, const float* __restrict__ E,
  float* __restrict__ partial)
{
  __shared__ float et[64*64];
  __shared__ float pb[128][66];
  __shared__ float sb[2][128];
  int tid = threadIdx.x, lane = tid&63, w = tid>>6;
  int bh = w & 1, ih = w >> 1;
  int b = bh*64 + lane;
  float vr[64];
  #pragma unroll
  for (int kk=0;kk<64;kk++) vr[kk] = vT[kk*128 + b];
  float acc[64];
  #pragma unroll
  for (int q=0;q<64;q++) acc[q]=0.f;
  float srun = 0.f;
  int start = blockIdx.x*CHUNK2;
  for (int sub=0; sub<3; ++sub){
    int i0 = start + sub*64;
    __syncthreads();
    #pragma unroll
    for (int it=0; it<4; ++it){
      int li = tid + it*256;              // 1024 float4 slots
      int item = li >> 4, d4 = li & 15;
      int gidx = i0 + item;
      float4 val = {0.f,0.f,0.f,0.f};
      if (gidx < NIT) val = ((const float4*)E)[(size_t)gidx*16 + d4];
      ((float4*)et)[item*16 + d4] = val;
    }
    __syncthreads();
    for (int t2=0; t2<32; ++t2){
      int item = ih*32 + t2;
      if (i0 + item >= NIT) break;
      const float4* ep = (const float4*)(et + item*64);
      float s0=0,s1=0,s2=0,s3=0;
      #pragma unroll
      for (int q=0;q<16;q++){
        float4 e = ep[q];
        s0 += e.x*vr[4*q]; s1 += e.y*vr[4*q+1]; s2 += e.z*vr[4*q+2]; s3 += e.w*vr[4*q+3];
      }
      float ex = fexp((s0+s1)+(s2+s3));
      srun += ex;
      #pragma unroll
      for (int q=0;q<16;q++){
        float4 e = ep[q];
        acc[4*q+0] += ex*e.x; acc[4*q+1] += ex*e.y; acc[4*q+2] += ex*e.z; acc[4*q+3] += ex*e.w;
      }
    }
  }
  __syncthreads();
  if (ih == 0){
    #pragma unroll
    for (int q=0;q<64;q++) pb[b][q] = acc[q];
    sb[0][b] = srun;
  }
  __syncthreads();
  if (ih == 1){
    #pragma unroll
    for (int q=0;q<64;q++) pb[b][q] += acc[q];
    sb[1][b] = srun;
  }
  __syncthreads();
  float* dst = partial + (size_t)(blockIdx.x & (NBUCKET-1))*8448;
  for (int it=0; it<33; ++it){
    int li = tid + it*256;                 // 8448 slots, use 65 of 66 per batch
    int bb = li/66, cc = li%66;
    if (cc < 64)      atomicAdd(dst+li, pb[bb][cc]);
    else if (cc == 64) atomicAdd(dst+li, sb[0][bb]+sb[1][bb]);
  }
}

__global__ __launch_bounds__(256) void k_pcomb(const float* __restrict__ partial, float* __restrict__ p)
{
  int id = blockIdx.x*256 + threadIdx.x;   // b*64+d
  int b = id>>6, d = id&63;
  float a = 0.f, s = 0.f;
  #pragma unroll
  for (int q=0;q<NBUCKET;q++){
    const float* pp = partial + (size_t)q*8448 + b*66;
    a += pp[d]; s += pp[64];
  }
  p[id] = a/s;
}

// ---------------- r[b][j][l] = sum_d cat(p,v)[b,j,d]*Wc[j][d][l] ----------------
__global__ __launch_bounds__(256) void k_r(const float* __restrict__ p, const float* __restrict__ v,
  const float* __restrict__ Wc, float* __restrict__ r, float* __restrict__ rT)
{
  int gid = blockIdx.x*256 + threadIdx.x;
  int l = gid & 15, j = (gid>>4)&63, b = gid>>10;
  const float* wc = Wc + ((size_t)j*80)*16 + l;
  const float* pbp = p + b*64;
  float acc = 0.f;
  #pragma unroll 8
  for (int d=0; d<64; ++d) acc += pbp[d]*wc[d*16];
  const float* vb = v + ((size_t)b*64 + j)*16;
  #pragma unroll
  for (int d=0; d<16; ++d) acc += vb[d]*wc[(64+d)*16];
  r[((size_t)b*64+j)*16 + l] = acc;
  rT[((size_t)b*16+l)*64 + j] = acc;
}

// ---------------- b[b][i][j] += sum_d u[b][i][d][j]*r[b][j][d], u recomputed ----------------
__global__ __launch_bounds__(256) void k_bupd(const float* __restrict__ behE, const float* __restrict__ W,
  const float* __restrict__ rT, float* __restrict__ bmat)
{
  int lane = threadIdx.x & 63;
  int idx = blockIdx.x*4 + (threadIdx.x>>6);   // b*64+i
  int b = idx >> 6, i = idx & 63;
  const float* be = behE + (size_t)idx*64;
  const float* rp = rT + (size_t)b*1024;
  float acc = 0.f;
  #pragma unroll
  for (int d=0; d<16; ++d){
    const float* wp = W + ((size_t)((i*16+d)*4))*64 + lane;
    float uu = be[d]*wp[0] + be[16+d]*wp[64] + be[32+d]*wp[128] + be[48+d]*wp[192];
    acc += uu * rp[d*64 + lane];
  }
  bmat[(size_t)idx*64 + lane] += acc;
}

// ---------------- logits: LDS-staged E tile, coalesced writes ----------------
__global__ __launch_bounds__(256) void k_logits(const float* __restrict__ vT, const float* __restrict__ E,
  float* __restrict__ out)
{
  __shared__ float et[64*64];       // 16 KB: 64 items x 64 dims
  __shared__ float tl[128][65];     // logits tile, padded
  int tid = threadIdx.x;
  int b = tid & 127, ih = tid >> 7;
  float vr[64];
  #pragma unroll
  for (int kk=0;kk<64;kk++) vr[kk] = vT[kk*128 + b];
  int i0 = blockIdx.x*64;
  #pragma unroll
  for (int it=0; it<4; ++it){
    int li = tid + it*256;          // 1024 float4 slots
    int item = li >> 4;
    int gidx = i0 + item;
    float4 val = {0.f,0.f,0.f,0.f};
    if (gidx < NIT) val = ((const float4*)E)[(size_t)gidx*16 + (li&15)];
    ((float4*)et)[li] = val;
  }
  __syncthreads();
  for (int t2=0; t2<32; ++t2){
    int item = ih*32 + t2;
    const float4* ep = (const float4*)(et + item*64);
    float s0=0,s1=0,s2=0,s3=0;
    #pragma unroll
    for (int q=0;q<16;q++){
      float4 e = ep[q];
      s0 += e.x*vr[4*q]; s1 += e.y*vr[4*q+1]; s2 += e.z*vr[4*q+2]; s3 += e.w*vr[4*q+3];
    }
    tl[b][item] = (s0+s1)+(s2+s3);
  }
  __syncthreads();
  for (int it=0; it<32; ++it){
    int li = tid + it*256;
    int row = li >> 6, col = li & 63;
    int i = i0 + col;
    if (i < NIT) out[(size_t)row*NIT + i] = tl[row][col];
  }
}

extern "C" void kernel_launch(void* const* d_in, const int* in_sizes, int n_in,
                              void* d_out, int out_size, void* d_ws, size_t ws_size,
                              hipStream_t stream)
{
  (void)in_sizes; (void)n_in; (void)out_size; (void)ws_size;
  const int*   s0 = (const int*)d_in[0];
  const int*   s1 = (const int*)d_in[1];
  const int*   s2 = (const int*)d_in[2];
  const int*   s3 = (const int*)d_in[3];
  const float* E  = (const float*)d_in[4];
  const float* W  = (const float*)d_in[5];
  const float* Wc = (const float*)d_in[6];
  const float* alpha = (const float*)d_in[7];
  const float* wv    = (const float*)d_in[8];
  const float* bias  = (const float*)d_in[9];
  const float* Wx = (const float*)d_in[10];
  const float* bx = (const float*)d_in[11];
  const float* Wh = (const float*)d_in[12];
  const float* bh = (const float*)d_in[13];

  char* ws = (char*)d_ws;
  size_t off = 0;
  auto alloc = [&](size_t bytes)->void*{ void* q = ws + off; off += (bytes + 255) & ~(size_t)255; return q; };
  u16*   gi   = (u16*)  alloc((size_t)M_*K_*T_*B_*48*2);   // 157.3 MB
  u16*   N1   = (u16*)  alloc((size_t)M_*K_*T_*B_*16*2);   // 52.4 MB
  u16*   xh   = (u16*)  alloc((size_t)M_*6400*64*2);
  u16*   xl   = (u16*)  alloc((size_t)M_*6400*64*2);
  u16*   wh   = (u16*)  alloc((size_t)M_*3072*64*2);
  u16*   wl   = (u16*)  alloc((size_t)M_*3072*64*2);
  float* bmat = (float*)alloc((size_t)B_*64*64*4);
  float* behE = (float*)alloc((size_t)B_*64*4*16*4);
  float* v    = (float*)alloc((size_t)B_*64*16*4);
  float* vT   = (float*)alloc((size_t)64*128*4);
  float* r1   = (float*)alloc((size_t)B_*64*16*4);
  float* rT1  = (float*)alloc((size_t)B_*64*16*4);
  float* r2   = (float*)alloc((size_t)B_*64*16*4);
  float* rT2  = (float*)alloc((size_t)B_*64*16*4);
  float* p    = (float*)alloc((size_t)B_*64*4);
  float* partial = (float*)alloc((size_t)NBUCKET*8448*4); // 270 KB
  // total ~227 MB

  hipMemsetAsync(bmat, 0, (size_t)B_*64*64*4, stream);
  k_prep_x<<<800,256,0,stream>>>(s0,s1,s2,s3,E,xh,xl);
  k_prep_w<<<192,256,0,stream>>>(Wx,wh,wl);
  k_gemm_gi<<<1024,256,0,stream>>>(xh,xl,wh,wl,bx,bh,gi);

  // ---- routing iteration 1 ----
  k_gru<0,1,0><<<2048,256,0,stream>>>(gi,Wh,bh,nullptr,N1,behE);
  k_cv<<<128,256,0,stream>>>(bmat,behE,W,alpha,wv,bias,v,vT);
  hipMemsetAsync(partial, 0, (size_t)NBUCKET*8448*4, stream);
  k_pfused<<<NBP2,256,0,stream>>>(vT,E,partial);
  k_pcomb<<<32,256,0,stream>>>(partial,p);
  k_r<<<512,256,0,stream>>>(p,v,Wc,r1,rT1);
  k_bupd<<<2048,256,0,stream>>>(behE,W,rT1,bmat);

  // ---- routing iteration 2: reads C1=N1*r1 live, folds into gi.z, overwrites N with n2 ----
  k_gru<1,1,1><<<2048,256,0,stream>>>(gi,Wh,bh,r1,N1,behE);
  k_cv<<<128,256,0,stream>>>(bmat,behE,W,alpha,wv,bias,v,vT);
  hipMemsetAsync(partial, 0, (size_t)NBUCKET*8448*4, stream);
  k_pfused<<<NBP2,256,0,stream>>>(vT,E,partial);
  k_pcomb<<<32,256,0,stream>>>(partial,p);
  k_r<<<512,256,0,stream>>>(p,v,Wc,r2,rT2);
  k_bupd<<<2048,256,0,stream>>>(behE,W,rT2,bmat);

  // ---- final pass: C = (folded C1) + N2*r2 live ----
  k_gru<1,0,0><<<2048,256,0,stream>>>(gi,Wh,bh,r2,N1,behE);
  k_cv<<<128,256,0,stream>>>(bmat,behE,W,alpha,wv,bias,v,vT);
  k_logits<<<1563,256,0,stream>>>(vT,E,(float*)d_out);
}

// Round 6
// 586.209 us; speedup vs baseline: 2.4867x; 1.4488x over previous
//
#include <hip/hip_runtime.h>
#include <hip/hip_bf16.h>
#include <cstdint>
#include <cstddef>

#define B_   128
#define T_   50
#define M_   4
#define D_   64
#define K_   64
#define L_   16
#define NIT  100001
#define NBP3 256
#define CHUNK3 391     /* 256*391 = 100096 >= NIT */
#define PSTRIDE 8320   /* 8192 p-words + 128 srun words per block slice */

typedef unsigned short u16;
typedef unsigned int   u32;
typedef __attribute__((ext_vector_type(8))) short short8;
typedef __attribute__((ext_vector_type(4))) float f32x4;

__device__ __forceinline__ float bf2f(u16 v){ u32 u = ((u32)v)<<16; float f; __builtin_memcpy(&f,&u,4); return f; }
__device__ __forceinline__ u16 f2bf(float f){
  u32 u; __builtin_memcpy(&u,&f,4);
  u32 r = (u + 0x7FFFu + ((u>>16)&1u)) >> 16;
  return (u16)r;
}
__device__ __forceinline__ float fexp(float x){ return __builtin_amdgcn_exp2f(x*1.4426950408889634f); }
__device__ __forceinline__ float fsig(float x){ return __builtin_amdgcn_rcpf(1.0f + fexp(-x)); }
__device__ __forceinline__ float ftanh(float x){ return 1.0f - 2.0f*__builtin_amdgcn_rcpf(1.0f + fexp(2.0f*x)); }
__device__ __forceinline__ void unpack8(const u32* s, short8& h, short8& l){
  #pragma unroll
  for (int q=0;q<8;q++){ h[q]=(short)(s[q]&0xFFFFu); l[q]=(short)(s[q]>>16); }
}

// ---------------- prep x: embed+mask, split fp32 -> bf16 hi/lo, layout [m][t*128+b][64] ----------------
__global__ __launch_bounds__(256) void k_prep_x(const int* __restrict__ s0, const int* __restrict__ s1,
  const int* __restrict__ s2, const int* __restrict__ s3, const float* __restrict__ E,
  u16* __restrict__ xh, u16* __restrict__ xl)
{
  int id = blockIdx.x*256 + threadIdx.x;
  int e8 = id & 7;
  int rm = id >> 3;
  int m = rm / 6400; int r = rm - m*6400;
  int t = r >> 7, b = r & 127;
  const int* sq = (m==0)? s0 : (m==1)? s1 : (m==2)? s2 : s3;
  int idx = sq[b*T_ + t];
  float sc = (idx==0)? 0.0f : 1.0f;
  const float4* ep = (const float4*)(E + (size_t)idx*64 + e8*8);
  float4 v0 = ep[0], v1 = ep[1];
  float vals[8] = {v0.x,v0.y,v0.z,v0.w,v1.x,v1.y,v1.z,v1.w};
  u32 hw[4], lw[4];
  #pragma unroll
  for (int q=0;q<4;q++){
    float f0 = vals[2*q]*sc, f1 = vals[2*q+1]*sc;
    u16 h0 = f2bf(f0), h1 = f2bf(f1);
    u16 l0 = f2bf(f0 - bf2f(h0)), l1 = f2bf(f1 - bf2f(h1));
    hw[q] = (u32)h0 | ((u32)h1<<16);
    lw[q] = (u32)l0 | ((u32)l1<<16);
  }
  size_t off = (size_t)rm*64 + e8*8;
  uint4 hv; hv.x=hw[0]; hv.y=hw[1]; hv.z=hw[2]; hv.w=hw[3];
  uint4 lv; lv.x=lw[0]; lv.y=lw[1]; lv.z=lw[2]; lv.w=lw[3];
  *(uint4*)(xh + off) = hv;
  *(uint4*)(xl + off) = lv;
}

// ---------------- prep W: transpose Wx[m][d][g] -> [m][g][d], split bf16 hi/lo ----------------
__global__ __launch_bounds__(256) void k_prep_w(const float* __restrict__ Wx,
  u16* __restrict__ wh, u16* __restrict__ wl)
{
  __shared__ float tl[64][65];
  int m = blockIdx.x / 48, gt = blockIdx.x % 48;
  for (int it=0; it<16; ++it){
    int li = threadIdx.x + it*256;
    int dl = li >> 6, gl = li & 63;
    tl[dl][gl] = Wx[((size_t)m*64 + dl)*3072 + gt*64 + gl];
  }
  __syncthreads();
  for (int it=0; it<2; ++it){
    int unit = threadIdx.x + it*256;
    int gl = unit >> 3, d8 = unit & 7;
    u32 hw[4], lw[4];
    #pragma unroll
    for (int q=0;q<4;q++){
      float f0 = tl[d8*8+2*q][gl], f1 = tl[d8*8+2*q+1][gl];
      u16 h0 = f2bf(f0), h1 = f2bf(f1);
      u16 l0 = f2bf(f0 - bf2f(h0)), l1 = f2bf(f1 - bf2f(h1));
      hw[q] = (u32)h0 | ((u32)h1<<16);
      lw[q] = (u32)l0 | ((u32)l1<<16);
    }
    size_t off = ((size_t)m*3072 + gt*64 + gl)*64 + d8*8;
    uint4 hv; hv.x=hw[0]; hv.y=hw[1]; hv.z=hw[2]; hv.w=hw[3];
    uint4 lv; lv.x=lw[0]; lv.y=lw[1]; lv.z=lw[2]; lv.w=lw[3];
    *(uint4*)(wh + off) = hv;
    *(uint4*)(wl + off) = lv;
  }
}

// ---------------- gi GEMM via MFMA (split-bf16), gate-plane output layout ----------------
__global__ __launch_bounds__(256) void k_gemm_gi(const u16* __restrict__ xh, const u16* __restrict__ xl,
  const u16* __restrict__ wh, const u16* __restrict__ wl,
  const float* __restrict__ bx, const float* __restrict__ bhp, u16* __restrict__ gi)
{
  int bi = blockIdx.x;
  int q4 = bi & 3; int k = (bi>>2)&63; int m = bi>>8;
  int wv = threadIdx.x>>6, lane = threadIdx.x&63;
  int n16 = lane & 15, quad = lane >> 4;

  short8 Ah[3][2], Al[3][2];
  #pragma unroll
  for (int gate=0; gate<3; ++gate){
    int g = gate*1024 + k*16 + n16;
    #pragma unroll
    for (int c=0; c<2; ++c){
      size_t aoff = ((size_t)(m*3072 + g))*64 + c*32 + quad*8;
      Ah[gate][c] = *(const short8*)(wh + aoff);
      Al[gate][c] = *(const short8*)(wl + aoff);
    }
  }
  float bias[3][4];
  #pragma unroll
  for (int gate=0; gate<3; ++gate){
    #pragma unroll
    for (int rg=0; rg<4; ++rg){
      int j = quad*4 + rg;
      int g = gate*1024 + k*16 + j;
      bias[gate][rg] = bx[m*3072 + g] + ((gate<2)? bhp[(m*64+k)*48 + gate*16 + j] : 0.0f);
    }
  }
  for (int i=0; i<25; ++i){
    int row = q4*1600 + (i*4+wv)*16 + n16;
    size_t xoff = ((size_t)(m*6400 + row))*64 + quad*8;
    short8 Bh0 = *(const short8*)(xh + xoff);
    short8 Bh1 = *(const short8*)(xh + xoff + 32);
    short8 Bl0 = *(const short8*)(xl + xoff);
    short8 Bl1 = *(const short8*)(xl + xoff + 32);
    #pragma unroll
    for (int gate=0; gate<3; ++gate){
      f32x4 acc = {bias[gate][0], bias[gate][1], bias[gate][2], bias[gate][3]};
      acc = __builtin_amdgcn_mfma_f32_16x16x32_bf16(Ah[gate][0], Bh0, acc, 0,0,0);
      acc = __builtin_amdgcn_mfma_f32_16x16x32_bf16(Ah[gate][1], Bh1, acc, 0,0,0);
      acc = __builtin_amdgcn_mfma_f32_16x16x32_bf16(Al[gate][0], Bh0, acc, 0,0,0);
      acc = __builtin_amdgcn_mfma_f32_16x16x32_bf16(Al[gate][1], Bh1, acc, 0,0,0);
      acc = __builtin_amdgcn_mfma_f32_16x16x32_bf16(Ah[gate][0], Bl0, acc, 0,0,0);
      acc = __builtin_amdgcn_mfma_f32_16x16x32_bf16(Ah[gate][1], Bl1, acc, 0,0,0);
      u32 w0 = (u32)f2bf(acc[0]) | ((u32)f2bf(acc[1])<<16);
      u32 w1 = (u32)f2bf(acc[2]) | ((u32)f2bf(acc[3])<<16);
      size_t go = (((size_t)(m*64+k)*3 + gate)*6400 + row)*16 + quad*4;
      uint2 st; st.x = w0; st.y = w1;
      *(uint2*)(gi + go) = st;
    }
  }
}

// ---------------- GRU scan: 16 lanes per (b,m,k) chain; plane layout + t+1 register prefetch ----------------
template<int RC, int WN, int FOLD>
__global__ __launch_bounds__(256,4) void k_gru(u16* __restrict__ gi, const float* __restrict__ Wh,
  const float* __restrict__ bhp, const float* __restrict__ rp,
  u16* __restrict__ Nbuf, float* __restrict__ behE)
{
  __shared__ float hbuf[256];
  int tid = threadIdx.x;
  int wave = tid>>6, lane = tid&63;
  int bg = lane>>4, j = lane&15;
  int bi = blockIdx.x;
  int bblk = bi & 7; bi >>= 3;
  int k = bi & 63; int m = bi >> 6;
  int b = bblk*16 + wave*4 + bg;
  float wr[16], wz[16], wn[16];
  const float* whp = Wh + ((size_t)(m*64+k)*16)*48;
  #pragma unroll
  for (int l=0;l<16;l++){
    wr[l] = whp[l*48 + j];
    wz[l] = whp[l*48 + 16 + j];
    wn[l] = whp[l*48 + 32 + j];
  }
  float bhn = bhp[(m*64+k)*48 + 32 + j];
  float rv = 0.f;
  if (RC) rv = rp[((size_t)b*64+k)*16 + j];
  float hown = 0.0f;
  hbuf[tid] = 0.0f;
  __builtin_amdgcn_wave_barrier();
  size_t pbase = ((size_t)(m*64+k)*3)*102400 + b*16 + j;
  const u16* gR = gi + pbase;
  u16*       gZ = gi + pbase + 102400;
  const u16* gN = gi + pbase + 204800;
  u16*       nP = Nbuf + ((size_t)(m*64+k))*102400 + b*16 + j;
  const float* hgrp = &hbuf[tid & ~15];
  float gir_c = bf2f(gR[0]);
  float giz_c = bf2f(gZ[0]);
  float gin_c = bf2f(gN[0]);
  float Nc = 0.f;
  if (RC) Nc = bf2f(nP[0]);
  for (int t=0;t<50;++t){
    float gir_n=0.f, giz_n=0.f, gin_n=0.f, Nn=0.f;
    if (t<49){
      int nxt = (t+1)*2048;
      gir_n = bf2f(gR[nxt]);
      giz_n = bf2f(gZ[nxt]);
      gin_n = bf2f(gN[nxt]);
      if (RC) Nn = bf2f(nP[nxt]);
    }
    float Ct = 0.0f;
    if (RC) Ct = Nc * rv;
    if (FOLD) gZ[t*2048] = f2bf(giz_c + Ct);
    float hv[16];
    *(float4*)&hv[0]  = ((const float4*)hgrp)[0];
    *(float4*)&hv[4]  = ((const float4*)hgrp)[1];
    *(float4*)&hv[8]  = ((const float4*)hgrp)[2];
    *(float4*)&hv[12] = ((const float4*)hgrp)[3];
    float ghr = 0.f, ghz = 0.f, ghn = bhn;
    #pragma unroll
    for (int l=0;l<16;l++){ ghr += hv[l]*wr[l]; ghz += hv[l]*wz[l]; ghn += hv[l]*wn[l]; }
    float rg = fsig(gir_c + ghr);
    float zg = fsig(giz_c + ghz + Ct);
    float ng = ftanh(gin_c + rg*ghn);
    float hn = ng + zg*(hown - ng);
    if (WN) nP[t*2048] = f2bf(ng);
    hown = hn;
    __builtin_amdgcn_wave_barrier();
    hbuf[tid] = hn;
    __builtin_amdgcn_wave_barrier();
    gir_c=gir_n; giz_c=giz_n; gin_c=gin_n; Nc=Nn;
  }
  behE[(((size_t)b*64 + k)*4 + m)*16 + j] = hown;
}

// ---------------- softmax(b)+v+v_ with on-the-fly u recompute ----------------
__global__ __launch_bounds__(256) void k_cv(const float* __restrict__ bmat, const float* __restrict__ behE,
  const float* __restrict__ W, const float* __restrict__ alpha, const float* __restrict__ wv,
  const float* __restrict__ bias, float* __restrict__ vout, float* __restrict__ vT)
{
  __shared__ float cm[64][65];
  __shared__ float vsh[64][17];
  __shared__ float besh[4096];
  int b = blockIdx.x, tid = threadIdx.x;
  for (int it=0; it<16; ++it){
    int li = tid + it*256;
    cm[li>>6][li&63] = bmat[(size_t)b*4096 + li];
    besh[li] = behE[(size_t)b*4096 + li];
  }
  __syncthreads();
  if (tid < 64){
    float mx = -1e30f;
    for (int jj=0;jj<64;jj++) mx = fmaxf(mx, cm[tid][jj]);
    float sm = 0.f;
    for (int jj=0;jj<64;jj++){ float e = fexp(cm[tid][jj]-mx); cm[tid][jj]=e; sm+=e; }
    float inv = 1.0f/sm;
    for (int jj=0;jj<64;jj++) cm[tid][jj] *= inv;
  }
  __syncthreads();
  int j = tid & 63, dq = tid>>6;
  float a0=0,a1=0,a2=0,a3=0;
  for (int i=0;i<64;++i){
    float cij = cm[i][j];
    #pragma unroll
    for (int q=0;q<4;++q){
      int d = dq*4+q;
      const float* wp = W + ((size_t)((i*16+d)*4))*64 + j;
      float uu = besh[i*64+d]*wp[0] + besh[i*64+16+d]*wp[64]
               + besh[i*64+32+d]*wp[128] + besh[i*64+48+d]*wp[192];
      float cu = cij*uu;
      if (q==0) a0 += cu; else if (q==1) a1 += cu; else if (q==2) a2 += cu; else a3 += cu;
    }
  }
  float al = alpha[0];
  a0*=al; a1*=al; a2*=al; a3*=al;
  vsh[j][dq*4]=a0; vsh[j][dq*4+1]=a1; vsh[j][dq*4+2]=a2; vsh[j][dq*4+3]=a3;
  float* vp = vout + ((size_t)b*64 + j)*16 + dq*4;
  vp[0]=a0; vp[1]=a1; vp[2]=a2; vp[3]=a3;
  __syncthreads();
  if (tid < 64){
    float s=0.f;
    #pragma unroll
    for (int dd=0; dd<16; ++dd){ float q = vsh[tid][dd]; s += q*q; }
    vT[tid*128 + b] = sqrtf(s)*wv[tid] + bias[tid];
  }
}

// ---------------- prep v_: vT[c][b] -> vBp[b][c] packed split-bf16 ----------------
__global__ __launch_bounds__(256) void k_prep_v(const float* __restrict__ vT, u32* __restrict__ vBp)
{
  int id = blockIdx.x*256 + threadIdx.x;   // b*64+c
  int b = id>>6, c = id&63;
  float v = vT[c*128 + b];
  u16 h = f2bf(v); u16 l = f2bf(v - bf2f(h));
  vBp[id] = (u32)h | ((u32)l<<16);
}

// ---------------- fused logits+exp+p via MFMA (split-bf16), private per-block partials ----------------
__global__ __launch_bounds__(256) void k_pfused(const u32* __restrict__ vBp, const float* __restrict__ E,
  float* __restrict__ partial)
{
  __shared__ u16 etAh[32*72], etAl[32*72];     // [item][c] pad 72
  __shared__ u16 etBh[64*32], etBl[64*32];     // [c/d][item]
  __shared__ u32 exT[128*36];                  // [b][item] packed h|l, pad 36
  int tid = threadIdx.x, lane = tid&63, w = tid>>6;
  int n16 = lane&15, quad = lane>>4;

  // preload v B-fragments (constant over items)
  short8 vh[2][2], vl[2][2];
  #pragma unroll
  for (int nt2=0; nt2<2; ++nt2){
    int b = (2*w+nt2)*16 + n16;
    #pragma unroll
    for (int s=0; s<2; ++s){
      u32 tmp[8];
      const u32* src = vBp + b*64 + s*32 + quad*8;
      #pragma unroll
      for (int q=0;q<8;q++) tmp[q]=src[q];
      unpack8(tmp, vh[nt2][s], vl[nt2][s]);
    }
  }
  f32x4 pacc[2][4];
  #pragma unroll
  for (int a2=0;a2<2;a2++)
    #pragma unroll
    for (int b2=0;b2<4;b2++){ pacc[a2][b2][0]=0.f; pacc[a2][b2][1]=0.f; pacc[a2][b2][2]=0.f; pacc[a2][b2][3]=0.f; }
  float srun[2] = {0.f, 0.f};

  int start = blockIdx.x*CHUNK3;
  int bend = start + CHUNK3; if (bend > NIT) bend = NIT;
  int sitem = tid>>3, sc0 = (tid&7)*8;
  for (int ch=0; ch<13; ++ch){
    int i0 = start + ch*32;
    if (i0 >= bend) break;
    // ---- stage 32-item E tile ----
    {
      int gidx = i0 + sitem;
      float vals[8];
      if (gidx < NIT){
        float4 a = ((const float4*)E)[(size_t)gidx*16 + (sc0>>2)];
        float4 b2 = ((const float4*)E)[(size_t)gidx*16 + (sc0>>2) + 1];
        vals[0]=a.x; vals[1]=a.y; vals[2]=a.z; vals[3]=a.w;
        vals[4]=b2.x; vals[5]=b2.y; vals[6]=b2.z; vals[7]=b2.w;
      } else {
        #pragma unroll
        for (int q=0;q<8;q++) vals[q]=0.f;
      }
      u16 hh[8], ll[8];
      #pragma unroll
      for (int q=0;q<8;q++){ hh[q]=f2bf(vals[q]); ll[q]=f2bf(vals[q]-bf2f(hh[q])); }
      *(short8*)(etAh + sitem*72 + sc0) = *(short8*)hh;
      *(short8*)(etAl + sitem*72 + sc0) = *(short8*)ll;
      #pragma unroll
      for (int q=0;q<8;q++){
        etBh[(sc0+q)*32 + sitem] = hh[q];
        etBl[(sc0+q)*32 + sitem] = ll[q];
      }
    }
    __syncthreads();
    // ---- GEMM1: logits[item][b], exp, write exT ----
    short8 Eh[2][2], El[2][2];
    #pragma unroll
    for (int mt=0; mt<2; ++mt)
      #pragma unroll
      for (int s=0; s<2; ++s){
        const u16* base = etAh + (mt*16 + n16)*72 + s*32 + quad*8;
        Eh[mt][s] = *(const short8*)base;
        El[mt][s] = *(const short8*)(base + 32*72);   // etAl follows etAh? NO - separate arrays
      }
    // fix: read etAl properly
    #pragma unroll
    for (int mt=0; mt<2; ++mt)
      #pragma unroll
      for (int s=0; s<2; ++s)
        El[mt][s] = *(const short8*)(etAl + (mt*16 + n16)*72 + s*32 + quad*8);
    #pragma unroll
    for (int mt=0; mt<2; ++mt){
      #pragma unroll
      for (int nt2=0; nt2<2; ++nt2){
        f32x4 a = {0.f,0.f,0.f,0.f};
        #pragma unroll
        for (int s=0; s<2; ++s){
          a = __builtin_amdgcn_mfma_f32_16x16x32_bf16(Eh[mt][s], vh[nt2][s], a, 0,0,0);
          a = __builtin_amdgcn_mfma_f32_16x16x32_bf16(Eh[mt][s], vl[nt2][s], a, 0,0,0);
          a = __builtin_amdgcn_mfma_f32_16x16x32_bf16(El[mt][s], vh[nt2][s], a, 0,0,0);
        }
        u32 packed[4];
        #pragma unroll
        for (int rg=0; rg<4; ++rg){
          int it_g = i0 + mt*16 + quad*4 + rg;
          float ex = (it_g < bend)? fexp(a[rg]) : 0.f;
          srun[nt2] += ex;
          u16 h = f2bf(ex); u16 l = f2bf(ex - bf2f(h));
          packed[rg] = (u32)h | ((u32)l<<16);
        }
        int bl = (2*w+nt2)*16 + n16;
        uint4 st; st.x=packed[0]; st.y=packed[1]; st.z=packed[2]; st.w=packed[3];
        *(uint4*)(exT + bl*36 + mt*16 + quad*4) = st;
      }
    }
    __syncthreads();
    // ---- GEMM2: p[b][d] += exp @ E ----
    short8 Xh[2], Xl[2];
    #pragma unroll
    for (int mt2=0; mt2<2; ++mt2){
      int bl = (2*w+mt2)*16 + n16;
      uint4 t0 = *(const uint4*)(exT + bl*36 + quad*8);
      uint4 t1 = *(const uint4*)(exT + bl*36 + quad*8 + 4);
      u32 tmp[8] = {t0.x,t0.y,t0.z,t0.w,t1.x,t1.y,t1.z,t1.w};
      unpack8(tmp, Xh[mt2], Xl[mt2]);
    }
    #pragma unroll
    for (int nt3=0; nt3<4; ++nt3){
      int d = nt3*16 + n16;
      short8 Bh = *(const short8*)(etBh + d*32 + quad*8);
      short8 Bl = *(const short8*)(etBl + d*32 + quad*8);
      #pragma unroll
      for (int mt2=0; mt2<2; ++mt2){
        pacc[mt2][nt3] = __builtin_amdgcn_mfma_f32_16x16x32_bf16(Xh[mt2], Bh, pacc[mt2][nt3], 0,0,0);
        pacc[mt2][nt3] = __builtin_amdgcn_mfma_f32_16x16x32_bf16(Xh[mt2], Bl, pacc[mt2][nt3], 0,0,0);
        pacc[mt2][nt3] = __builtin_amdgcn_mfma_f32_16x16x32_bf16(Xl[mt2], Bh, pacc[mt2][nt3], 0,0,0);
      }
    }
    __syncthreads();
  }
  // ---- epilogue: private partial slice ----
  float* dst = partial + (size_t)blockIdx.x*PSTRIDE;
  #pragma unroll
  for (int mt2=0; mt2<2; ++mt2)
    #pragma unroll
    for (int nt3=0; nt3<4; ++nt3)
      #pragma unroll
      for (int rg=0; rg<4; ++rg){
        int b_g = (2*w+mt2)*16 + quad*4 + rg;
        int d_g = nt3*16 + n16;
        dst[b_g*64 + d_g] = pacc[mt2][nt3][rg];
      }
  #pragma unroll
  for (int nt2=0; nt2<2; ++nt2){
    float vsum = srun[nt2];
    vsum += __shfl_xor(vsum, 16);
    vsum += __shfl_xor(vsum, 32);
    if (quad == 0) dst[8192 + (2*w+nt2)*16 + n16] = vsum;
  }
}

__global__ __launch_bounds__(256) void k_pcomb(const float* __restrict__ partial, float* __restrict__ p)
{
  int id = blockIdx.x*256 + threadIdx.x;   // b*64+d
  int b = id>>6;
  float a = 0.f, s = 0.f;
  for (int q=0;q<NBP3;q++){
    a += partial[(size_t)q*PSTRIDE + id];
    s += partial[(size_t)q*PSTRIDE + 8192 + b];
  }
  p[id] = a/s;
}

// ---------------- r[b][j][l] = sum_d cat(p,v)[b,j,d]*Wc[j][d][l] ----------------
__global__ __launch_bounds__(256) void k_r(const float* __restrict__ p, const float* __restrict__ v,
  const float* __restrict__ Wc, float* __restrict__ r, float* __restrict__ rT)
{
  int gid = blockIdx.x*256 + threadIdx.x;
  int l = gid & 15, j = (gid>>4)&63, b = gid>>10;
  const float* wc = Wc + ((size_t)j*80)*16 + l;
  const float* pbp = p + b*64;
  float acc = 0.f;
  #pragma unroll 8
  for (int d=0; d<64; ++d) acc += pbp[d]*wc[d*16];
  const float* vb = v + ((size_t)b*64 + j)*16;
  #pragma unroll
  for (int d=0; d<16; ++d) acc += vb[d]*wc[(64+d)*16];
  r[((size_t)b*64+j)*16 + l] = acc;
  rT[((size_t)b*16+l)*64 + j] = acc;
}

// ---------------- b[b][i][j] += sum_d u[b][i][d][j]*r[b][j][d], u recomputed ----------------
__global__ __launch_bounds__(256) void k_bupd(const float* __restrict__ behE, const float* __restrict__ W,
  const float* __restrict__ rT, float* __restrict__ bmat)
{
  int lane = threadIdx.x & 63;
  int idx = blockIdx.x*4 + (threadIdx.x>>6);
  int b = idx >> 6, i = idx & 63;
  const float* be = behE + (size_t)idx*64;
  const float* rp = rT + (size_t)b*1024;
  float acc = 0.f;
  #pragma unroll
  for (int d=0; d<16; ++d){
    const float* wp = W + ((size_t)((i*16+d)*4))*64 + lane;
    float uu = be[d]*wp[0] + be[16+d]*wp[64] + be[32+d]*wp[128] + be[48+d]*wp[192];
    acc += uu * rp[d*64 + lane];
  }
  bmat[(size_t)idx*64 + lane] += acc;
}

// ---------------- final logits via MFMA (split-bf16), coalesced out[b][i] ----------------
__global__ __launch_bounds__(256) void k_logits(const u32* __restrict__ vBp, const float* __restrict__ E,
  float* __restrict__ out)
{
  __shared__ u16 etAh[64*72], etAl[64*72];   // [item][c] pad 72
  __shared__ float lt[128*68];               // [b][item] pad 68
  int tid = threadIdx.x, lane = tid&63, w = tid>>6;
  int n16 = lane&15, quad = lane>>4;
  // preload v B-fragments
  short8 vh[2][2], vl[2][2];
  #pragma unroll
  for (int nt2=0; nt2<2; ++nt2){
    int b = (2*w+nt2)*16 + n16;
    #pragma unroll
    for (int s=0; s<2; ++s){
      u32 tmp[8];
      const u32* src = vBp + b*64 + s*32 + quad*8;
      #pragma unroll
      for (int q=0;q<8;q++) tmp[q]=src[q];
      unpack8(tmp, vh[nt2][s], vl[nt2][s]);
    }
  }
  int i0 = blockIdx.x*64;
  // stage 64 items
  {
    int sitem = tid>>2, sc0 = (tid&3)*16;
    int gidx = i0 + sitem;
    float vals[16];
    if (gidx < NIT){
      #pragma unroll
      for (int q=0;q<4;q++){
        float4 a = ((const float4*)E)[(size_t)gidx*16 + (sc0>>2) + q];
        vals[4*q]=a.x; vals[4*q+1]=a.y; vals[4*q+2]=a.z; vals[4*q+3]=a.w;
      }
    } else {
      #pragma unroll
      for (int q=0;q<16;q++) vals[q]=0.f;
    }
    u16 hh[16], ll[16];
    #pragma unroll
    for (int q=0;q<16;q++){ hh[q]=f2bf(vals[q]); ll[q]=f2bf(vals[q]-bf2f(hh[q])); }
    *(short8*)(etAh + sitem*72 + sc0)     = *(short8*)hh;
    *(short8*)(etAh + sitem*72 + sc0 + 8) = *(short8*)(hh+8);
    *(short8*)(etAl + sitem*72 + sc0)     = *(short8*)ll;
    *(short8*)(etAl + sitem*72 + sc0 + 8) = *(short8*)(ll+8);
  }
  __syncthreads();
  #pragma unroll
  for (int mt=0; mt<4; ++mt){
    short8 Eh[2], El[2];
    #pragma unroll
    for (int s=0; s<2; ++s){
      Eh[s] = *(const short8*)(etAh + (mt*16 + n16)*72 + s*32 + quad*8);
      El[s] = *(const short8*)(etAl + (mt*16 + n16)*72 + s*32 + quad*8);
    }
    #pragma unroll
    for (int nt2=0; nt2<2; ++nt2){
      f32x4 a = {0.f,0.f,0.f,0.f};
      #pragma unroll
      for (int s=0; s<2; ++s){
        a = __builtin_amdgcn_mfma_f32_16x16x32_bf16(Eh[s], vh[nt2][s], a, 0,0,0);
        a = __builtin_amdgcn_mfma_f32_16x16x32_bf16(Eh[s], vl[nt2][s], a, 0,0,0);
        a = __builtin_amdgcn_mfma_f32_16x16x32_bf16(El[s], vh[nt2][s], a, 0,0,0);
      }
      int b = (2*w+nt2)*16 + n16;
      *(float4*)(lt + b*68 + mt*16 + quad*4) = *(float4*)&a;
    }
  }
  __syncthreads();
  int col = tid & 63, rgp = tid >> 6;
  if (i0 + col < NIT){
    #pragma unroll
    for (int rr=0; rr<32; ++rr){
      int b = rgp*32 + rr;
      out[(size_t)b*NIT + i0 + col] = lt[b*68 + col];
    }
  }
}

extern "C" void kernel_launch(void* const* d_in, const int* in_sizes, int n_in,
                              void* d_out, int out_size, void* d_ws, size_t ws_size,
                              hipStream_t stream)
{
  (void)in_sizes; (void)n_in; (void)out_size; (void)ws_size;
  const int*   s0 = (const int*)d_in[0];
  const int*   s1 = (const int*)d_in[1];
  const int*   s2 = (const int*)d_in[2];
  const int*   s3 = (const int*)d_in[3];
  const float* E  = (const float*)d_in[4];
  const float* W  = (const float*)d_in[5];
  const float* Wc = (const float*)d_in[6];
  const float* alpha = (const float*)d_in[7];
  const float* wv    = (const float*)d_in[8];
  const float* bias  = (const float*)d_in[9];
  const float* Wx = (const float*)d_in[10];
  const float* bx = (const float*)d_in[11];
  const float* Wh = (const float*)d_in[12];
  const float* bh = (const float*)d_in[13];

  char* ws = (char*)d_ws;
  size_t off = 0;
  auto alloc = [&](size_t bytes)->void*{ void* q = ws + off; off += (bytes + 255) & ~(size_t)255; return q; };
  u16*   gi   = (u16*)  alloc((size_t)M_*K_*T_*B_*48*2);   // 157.3 MB
  u16*   N1   = (u16*)  alloc((size_t)M_*K_*T_*B_*16*2);   // 52.4 MB
  u16*   xh   = (u16*)  alloc((size_t)M_*6400*64*2);
  u16*   xl   = (u16*)  alloc((size_t)M_*6400*64*2);
  u16*   wh   = (u16*)  alloc((size_t)M_*3072*64*2);
  u16*   wl   = (u16*)  alloc((size_t)M_*3072*64*2);
  float* bmat = (float*)alloc((size_t)B_*64*64*4);
  float* behE = (float*)alloc((size_t)B_*64*4*16*4);
  float* v    = (float*)alloc((size_t)B_*64*16*4);
  float* vT   = (float*)alloc((size_t)64*128*4);
  u32*   vBp  = (u32*)  alloc((size_t)128*64*4);
  float* r1   = (float*)alloc((size_t)B_*64*16*4);
  float* rT1  = (float*)alloc((size_t)B_*64*16*4);
  float* r2   = (float*)alloc((size_t)B_*64*16*4);
  float* rT2  = (float*)alloc((size_t)B_*64*16*4);
  float* p    = (float*)alloc((size_t)B_*64*4);
  float* partial = (float*)alloc((size_t)NBP3*PSTRIDE*4); // 8.5 MB
  // total ~235 MB

  hipMemsetAsync(bmat, 0, (size_t)B_*64*64*4, stream);
  k_prep_x<<<800,256,0,stream>>>(s0,s1,s2,s3,E,xh,xl);
  k_prep_w<<<192,256,0,stream>>>(Wx,wh,wl);
  k_gemm_gi<<<1024,256,0,stream>>>(xh,xl,wh,wl,bx,bh,gi);

  // ---- routing iteration 1 ----
  k_gru<0,1,0><<<2048,256,0,stream>>>(gi,Wh,bh,nullptr,N1,behE);
  k_cv<<<128,256,0,stream>>>(bmat,behE,W,alpha,wv,bias,v,vT);
  k_prep_v<<<32,256,0,stream>>>(vT,vBp);
  k_pfused<<<NBP3,256,0,stream>>>(vBp,E,partial);
  k_pcomb<<<32,256,0,stream>>>(partial,p);
  k_r<<<512,256,0,stream>>>(p,v,Wc,r1,rT1);
  k_bupd<<<2048,256,0,stream>>>(behE,W,rT1,bmat);

  // ---- routing iteration 2: reads C1=N1*r1 live, folds into gi.z, overwrites N with n2 ----
  k_gru<1,1,1><<<2048,256,0,stream>>>(gi,Wh,bh,r1,N1,behE);
  k_cv<<<128,256,0,stream>>>(bmat,behE,W,alpha,wv,bias,v,vT);
  k_prep_v<<<32,256,0,stream>>>(vT,vBp);
  k_pfused<<<NBP3,256,0,stream>>>(vBp,E,partial);
  k_pcomb<<<32,256,0,stream>>>(partial,p);
  k_r<<<512,256,0,stream>>>(p,v,Wc,r2,rT2);
  k_bupd<<<2048,256,0,stream>>>(behE,W,rT2,bmat);

  // ---- final pass: C = (folded C1) + N2*r2 live ----
  k_gru<1,0,0><<<2048,256,0,stream>>>(gi,Wh,bh,r2,N1,behE);
  k_cv<<<128,256,0,stream>>>(bmat,behE,W,alpha,wv,bias,v,vT);
  k_prep_v<<<32,256,0,stream>>>(vT,vBp);
  k_logits<<<1563,256,0,stream>>>(vBp,E,(float*)d_out);
}